// Round 10
// baseline (735.445 us; speedup 1.0000x reference)
//
#include <hip/hip_runtime.h>

#define NN 100000        // nodes
#define NE 1600000       // edges
#define NRL 3            // relations
#define NG 1024          // graphs
#define NBUCK 3125       // NN/32 buckets of 32 nodes
#define NXCD 8
#define PSTRIDE 128      // slots per (bucket, xcd): mean 64, sigma 8 -> +8 sigma
#define BSLOTS (NXCD * PSTRIDE)   // 1024 slots per bucket
#define OSTRIDE 104      // u16 offsets per bucket (96 starts + total, padded)

__device__ __forceinline__ int xcd_id() {
    unsigned int x;
    asm volatile("s_getreg_b32 %0, hwreg(HW_REG_XCC_ID)" : "=s"(x));
    return (int)(x & 7);
}

// ---------------- embed + lin0 + relu ----------------
__global__ void k_embed(const int* __restrict__ x_idx,
                        const float* __restrict__ semb, const float* __restrict__ cemb,
                        const float* __restrict__ w, const float* __restrict__ b,
                        float* __restrict__ xout) {
    __shared__ float s_w[16 * 64];
    __shared__ float s_se[64], s_ce[64], s_b[64];
    int t = threadIdx.x;
    for (int i = t; i < 16 * 64; i += 256) s_w[i] = w[i];
    if (t < 64) { s_se[t] = semb[t]; s_ce[t] = cemb[t]; s_b[t] = b[t]; }
    __syncthreads();
    int gid = blockIdx.x * 256 + t;           // grid exactly NN*64/256
    int v = gid >> 6, h = gid & 63;
    int si = x_idx[2 * v], ci = x_idx[2 * v + 1];
    float acc = s_b[h];
#pragma unroll
    for (int d = 0; d < 8; ++d) acc += s_se[si * 8 + d] * s_w[d * 64 + h];
#pragma unroll
    for (int d = 0; d < 8; ++d) acc += s_ce[ci * 8 + d] * s_w[(8 + d) * 64 + h];
    xout[gid] = fmaxf(acc, 0.f);
}

// ---------------- bucket build: XCD-private append of packed edge records ----------------
// rec = src (17b) | rel<<17 (2b) | (dst&31)<<19 (5b)
__global__ void k_bucket(const int* __restrict__ ei, const int* __restrict__ et,
                         int* __restrict__ bcnt, unsigned int* __restrict__ arena) {
    int e = blockIdx.x * 256 + threadIdx.x;
    if (e >= NE) return;
    int p = xcd_id();                          // wave-uniform physical XCD
    int src = ei[e];
    int dst = ei[NE + e];
    int rel = et[e];
    int b = dst >> 5;
    unsigned int rec = (unsigned int)src | ((unsigned int)rel << 17) |
                       ((unsigned int)(dst & 31) << 19);
    int cell = b * NXCD + p;
    int pos = atomicAdd(&bcnt[cell], 1);
    if (pos < PSTRIDE) arena[(size_t)cell * PSTRIDE + pos] = rec;
}

// ---------------- per-bucket LDS counting sort: 8 partitions -> sorted src + offsets ----------------
// key = dstlo*3 + rel (96 keys). Packed sorted writeback at bucket base (stride BSLOTS).
__global__ __launch_bounds__(256) void k_sortbucket(
        const int* __restrict__ bcnt, unsigned int* __restrict__ arena,
        unsigned short* __restrict__ off16) {
    __shared__ unsigned int s_rec[BSLOTS];
    __shared__ unsigned int s_srt[BSLOTS];
    __shared__ int s_hist[97], s_start[97], s_pos[96];
    int t = threadIdx.x;
    int b = blockIdx.x;

    if (t < 97) s_hist[t] = 0;
    __syncthreads();

    int tot = 0;
#pragma unroll
    for (int p = 0; p < NXCD; ++p) {
        int c = bcnt[b * NXCD + p]; if (c > PSTRIDE) c = PSTRIDE;
        const unsigned int* src = arena + ((size_t)(b * NXCD + p)) * PSTRIDE;
        for (int i = t; i < c; i += 256) {
            unsigned int r = src[i];
            s_rec[tot + i] = r;
            int key = ((r >> 19) & 31) * 3 + ((r >> 17) & 3);
            atomicAdd(&s_hist[key], 1);
        }
        tot += c;
    }
    __syncthreads();
    if (t == 0) {
        int run = 0;
#pragma unroll 8
        for (int k = 0; k < 96; ++k) { s_start[k] = run; run += s_hist[k]; }
        s_start[96] = run;                 // == tot
    }
    __syncthreads();
    if (t < 96) s_pos[t] = s_start[t];
    __syncthreads();
    for (int i = t; i < tot; i += 256) {
        unsigned int r = s_rec[i];
        int key = ((r >> 19) & 31) * 3 + ((r >> 17) & 3);
        int p = atomicAdd(&s_pos[key], 1);
        s_srt[p] = r & 0x1FFFF;            // keep src only
    }
    __syncthreads();
    for (int i = t; i < tot; i += 256)      // coalesced packed writeback at bucket base
        arena[(size_t)b * BSLOTS + i] = s_srt[i];
    if (t < 97) off16[(size_t)b * OSTRIDE + t] = (unsigned short)s_start[t];
}

// ---------------- per-(r,dst) mean aggregation: wave per node ----------------
// Fused loop over the node's sorted edge range; relation by boundary compare.
// Writes K[v][0:64)=mean_r0, [64:128)=mean_r1, [128:192)=mean_r2, [192:256)=x[v]
__global__ void k_agg(const float* __restrict__ xin, const unsigned int* __restrict__ arena,
                      const unsigned short* __restrict__ off16, float* __restrict__ K) {
    int wid = (blockIdx.x * 256 + threadIdx.x) >> 6;
    int lane = threadIdx.x & 63;
    if (wid >= NN) return;
    int v = wid;
    int b = v >> 5, dlo = v & 31;
    const unsigned short* ofs = off16 + (size_t)b * OSTRIDE + dlo * 3;
    int s0 = __builtin_amdgcn_readfirstlane((int)ofs[0]);
    int s1 = __builtin_amdgcn_readfirstlane((int)ofs[1]);
    int s2 = __builtin_amdgcn_readfirstlane((int)ofs[2]);
    int s3 = __builtin_amdgcn_readfirstlane((int)ofs[3]);
    const unsigned int* base = arena + (size_t)b * BSLOTS;

    float a0 = 0.f, a1 = 0.f, a2 = 0.f;
    int e = s0;
    for (; e + 8 <= s3; e += 8) {
#pragma unroll
        for (int k = 0; k < 8; ++k) {
            int ee = e + k;
            int idx = (int)base[ee];                  // uniform -> s_load
            float x = xin[(size_t)idx * 64 + lane];   // coalesced 256B gather
            a0 += (ee < s1) ? x : 0.f;
            a1 += (ee >= s1 && ee < s2) ? x : 0.f;
            a2 += (ee >= s2) ? x : 0.f;
        }
    }
    for (; e < s3; ++e) {
        int idx = (int)base[e];
        float x = xin[(size_t)idx * 64 + lane];
        a0 += (e < s1) ? x : 0.f;
        a1 += (e >= s1 && e < s2) ? x : 0.f;
        a2 += (e >= s2) ? x : 0.f;
    }

    float* Kv = K + (size_t)v * 256;
    Kv[lane]       = a0 / fmaxf((float)(s1 - s0), 1.f);
    Kv[64 + lane]  = a1 / fmaxf((float)(s2 - s1), 1.f);
    Kv[128 + lane] = a2 / fmaxf((float)(s3 - s2), 1.f);
    Kv[192 + lane] = xin[(size_t)v * 64 + lane];
}

// ---------------- dense transform: xout = relu(K @ [Wr0;Wr1;Wr2;Wroot] + b) ----------------
// LANE = NODE, H SPLIT ACROSS WAVES. Block = 256 thr = 64 nodes; wave w computes
// h in [16w,16w+16) for all 64 nodes -> acc[16]/lane (no spill possible).
// K streamed in 16-d chunks: ONE coalesced float4 load per thread per chunk
// (64B-line granular) -> shared [2][64][21] tile (pad 21: conflict-free both ways,
// double-buffered, 2 barriers/chunk) -> per-lane ds_read_b128.
// W is wave-uniform (4 rows x 16 h per d4 = 64 scalars) -> s_load, SGPR FMA operand.
// Inner body per d4: 1 ds_read_b128 + 4 s_load + 64 pure v_fmac_f32.
__global__ __launch_bounds__(256) void k_transform(
        const float* __restrict__ K, const float* __restrict__ wrel,
        const float* __restrict__ wroot, const float* __restrict__ b,
        float* __restrict__ xout) {
    __shared__ float s_k[2][64][21];
    int t = threadIdx.x, wave = t >> 6, lane = t & 63;
    int v0 = blockIdx.x * 64;
    int v = v0 + lane;
    int h0 = wave * 16;

    // staging: thread t covers row t>>2 (0..63), cols (t&3)*4 of the 16-d chunk
    int srow = t >> 2;
    int scol = (t & 3) * 4;
    int vs = v0 + srow; if (vs >= NN) vs = NN - 1;     // clamp tail rows
    const float* gk = K + (size_t)vs * 256 + scol;

    float4 kv = *reinterpret_cast<const float4*>(gk);  // chunk 0

    float acc[16];
#pragma unroll
    for (int j = 0; j < 16; ++j) acc[j] = 0.f;

    for (int c = 0; c < 16; ++c) {
        __syncthreads();                                // prev compute done
        *reinterpret_cast<float4*>(&s_k[c & 1][srow][scol]) = kv;
        if (c < 15)
            kv = *reinterpret_cast<const float4*>(gk + (c + 1) * 16);  // in flight during compute
        __syncthreads();                                // stage visible
#pragma unroll
        for (int d4 = 0; d4 < 4; ++d4) {
            float4 kr = *reinterpret_cast<const float4*>(&s_k[c & 1][lane][d4 * 4]);
            int rb = c * 16 + d4 * 4;                   // uniform global d row
            const float* Wp = (rb < 192) ? (wrel + (size_t)rb * 64 + h0)
                                         : (wroot + (size_t)(rb - 192) * 64 + h0);
#pragma unroll
            for (int j = 0; j < 16; ++j) {              // W uniform -> s_load operand
                acc[j] += kr.x * Wp[0 * 64 + j];
                acc[j] += kr.y * Wp[1 * 64 + j];
                acc[j] += kr.z * Wp[2 * 64 + j];
                acc[j] += kr.w * Wp[3 * 64 + j];
            }
        }
    }

    if (v < NN) {
        float* op = xout + (size_t)v * 64 + h0;
#pragma unroll
        for (int q = 0; q < 4; ++q) {
            float4 o;
            o.x = fmaxf(acc[q * 4 + 0] + b[h0 + q * 4 + 0], 0.f);
            o.y = fmaxf(acc[q * 4 + 1] + b[h0 + q * 4 + 1], 0.f);
            o.z = fmaxf(acc[q * 4 + 2] + b[h0 + q * 4 + 2], 0.f);
            o.w = fmaxf(acc[q * 4 + 3] + b[h0 + q * 4 + 3], 0.f);
            *reinterpret_cast<float4*>(op + q * 4) = o;
        }
    }
}

// ---------------- global mean pool: wave-segmented over sorted batch ----------------
#define POOL_CHUNK 32
__global__ void k_pool(const float* __restrict__ x, const int* __restrict__ batch,
                       float* __restrict__ psum, int* __restrict__ pcnt) {
    int gwid = (blockIdx.x * 256 + threadIdx.x) >> 6;
    int lane = threadIdx.x & 63;
    int v0 = gwid * POOL_CHUNK;
    if (v0 >= NN) return;
    int v1 = v0 + POOL_CHUNK; if (v1 > NN) v1 = NN;
    float acc = 0.f;
    int cnt = 0;
    int gcur = batch[v0];
    for (int v = v0; v < v1; ++v) {
        int g = batch[v];
        if (g != gcur) {
            atomicAdd(&psum[gcur * 64 + lane], acc);
            if (lane == 0) atomicAdd(&pcnt[gcur], cnt);
            acc = 0.f; cnt = 0; gcur = g;
        }
        acc += x[(size_t)v * 64 + lane];
        ++cnt;
    }
    atomicAdd(&psum[gcur * 64 + lane], acc);
    if (lane == 0) atomicAdd(&pcnt[gcur], cnt);
}

__global__ void k_cls(const float* __restrict__ psum, const int* __restrict__ pcnt,
                      const float* __restrict__ w, const float* __restrict__ b,
                      float* __restrict__ out) {
    int gid = blockIdx.x * 256 + threadIdx.x;
    if (gid >= NG * 10) return;
    int g = gid / 10, c = gid % 10;
    float inv = 1.f / fmaxf((float)pcnt[g], 1.f);
    float acc = 0.f;
#pragma unroll
    for (int d = 0; d < 64; ++d) acc += psum[g * 64 + d] * w[d * 10 + c];
    out[gid] = acc * inv + b[c];
}

extern "C" void kernel_launch(void* const* d_in, const int* in_sizes, int n_in,
                              void* d_out, int out_size, void* d_ws, size_t ws_size,
                              hipStream_t stream) {
    const int*   x_idx  = (const int*)d_in[0];
    const int*   ei     = (const int*)d_in[1];
    const int*   et     = (const int*)d_in[2];
    const int*   batch  = (const int*)d_in[3];
    const float* semb   = (const float*)d_in[4];
    const float* cemb   = (const float*)d_in[5];
    const float* lin0w  = (const float*)d_in[6];
    const float* lin0b  = (const float*)d_in[7];
    const float* r1wrel = (const float*)d_in[8];
    const float* r1wroot= (const float*)d_in[9];
    const float* r1b    = (const float*)d_in[10];
    const float* r2wrel = (const float*)d_in[11];
    const float* r2wroot= (const float*)d_in[12];
    const float* r2b    = (const float*)d_in[13];
    const float* clsw   = (const float*)d_in[14];
    const float* clsb   = (const float*)d_in[15];
    float* out = (float*)d_out;

    char* ws = (char*)d_ws;
    size_t o = 0;
    auto alloc = [&](size_t bytes) -> void* {
        void* p = ws + o;
        o += (bytes + 255) & ~(size_t)255;
        return p;
    };
    int*            bcnt  = (int*)           alloc((size_t)NBUCK * NXCD * 4);
    unsigned int*   arena = (unsigned int*)  alloc((size_t)NBUCK * BSLOTS * 4);
    unsigned short* off16 = (unsigned short*)alloc((size_t)NBUCK * OSTRIDE * 2);
    float*          xA    = (float*)         alloc((size_t)NN * 64 * 4);
    float*          xB    = (float*)         alloc((size_t)NN * 64 * 4);
    float*          Kbuf  = (float*)         alloc((size_t)NN * 256 * 4);
    float*          psum  = (float*)         alloc((size_t)NG * 64 * 4);
    int*            pcnt  = (int*)           alloc((size_t)NG * 4);

    hipMemsetAsync(bcnt, 0, (size_t)NBUCK * NXCD * 4, stream);
    hipMemsetAsync(psum, 0, (size_t)NG * 64 * 4, stream);
    hipMemsetAsync(pcnt, 0, (size_t)NG * 4, stream);

    // node features
    k_embed<<<NN * 64 / 256, 256, 0, stream>>>(x_idx, semb, cemb, lin0w, lin0b, xA);

    // bucket build (XCD-private) + per-bucket counting sort (once, reused by both layers)
    k_bucket<<<NE / 256, 256, 0, stream>>>(ei, et, bcnt, arena);
    k_sortbucket<<<NBUCK, 256, 0, stream>>>(bcnt, arena, off16);

    // layer 1
    k_agg<<<NN / 4, 256, 0, stream>>>(xA, arena, off16, Kbuf);
    k_transform<<<(NN + 63) / 64, 256, 0, stream>>>(Kbuf, r1wrel, r1wroot, r1b, xB);
    // layer 2
    k_agg<<<NN / 4, 256, 0, stream>>>(xB, arena, off16, Kbuf);
    k_transform<<<(NN + 63) / 64, 256, 0, stream>>>(Kbuf, r2wrel, r2wroot, r2b, xA);

    // pool + classify
    {
        int nwaves = (NN + POOL_CHUNK - 1) / POOL_CHUNK;        // 3125
        int nblk = (nwaves * 64 + 255) / 256;                   // 782
        k_pool<<<nblk, 256, 0, stream>>>(xA, batch, psum, pcnt);
    }
    k_cls<<<(NG * 10 + 255) / 256, 256, 0, stream>>>(psum, pcnt, clsw, clsb, out);
}

// Round 11
// 502.340 us; speedup vs baseline: 1.4640x; 1.4640x over previous
//
#include <hip/hip_runtime.h>

#define NN 100000        // nodes
#define NE 1600000       // edges
#define NRL 3            // relations
#define NG 1024          // graphs
#define NBUCK 3125       // NN/32 buckets of 32 nodes
#define NXCD 8
#define PSTRIDE 128      // slots per (bucket, xcd): mean 64, sigma 8 -> +8 sigma
#define BSLOTS (NXCD * PSTRIDE)   // 1024 slots per bucket
#define OSTRIDE 104      // u16 offsets per bucket (96 starts + total, padded)

typedef __attribute__((ext_vector_type(8))) float f32x8;

__device__ __forceinline__ int xcd_id() {
    unsigned int x;
    asm volatile("s_getreg_b32 %0, hwreg(HW_REG_XCC_ID)" : "=s"(x));
    return (int)(x & 7);
}

// ---------------- embed + lin0 + relu ----------------
__global__ void k_embed(const int* __restrict__ x_idx,
                        const float* __restrict__ semb, const float* __restrict__ cemb,
                        const float* __restrict__ w, const float* __restrict__ b,
                        float* __restrict__ xout) {
    __shared__ float s_w[16 * 64];
    __shared__ float s_se[64], s_ce[64], s_b[64];
    int t = threadIdx.x;
    for (int i = t; i < 16 * 64; i += 256) s_w[i] = w[i];
    if (t < 64) { s_se[t] = semb[t]; s_ce[t] = cemb[t]; s_b[t] = b[t]; }
    __syncthreads();
    int gid = blockIdx.x * 256 + t;           // grid exactly NN*64/256
    int v = gid >> 6, h = gid & 63;
    int si = x_idx[2 * v], ci = x_idx[2 * v + 1];
    float acc = s_b[h];
#pragma unroll
    for (int d = 0; d < 8; ++d) acc += s_se[si * 8 + d] * s_w[d * 64 + h];
#pragma unroll
    for (int d = 0; d < 8; ++d) acc += s_ce[ci * 8 + d] * s_w[(8 + d) * 64 + h];
    xout[gid] = fmaxf(acc, 0.f);
}

// ---------------- bucket build: XCD-private append of packed edge records ----------------
// rec = src (17b) | rel<<17 (2b) | (dst&31)<<19 (5b)
__global__ void k_bucket(const int* __restrict__ ei, const int* __restrict__ et,
                         int* __restrict__ bcnt, unsigned int* __restrict__ arena) {
    int e = blockIdx.x * 256 + threadIdx.x;
    if (e >= NE) return;
    int p = xcd_id();                          // wave-uniform physical XCD
    int src = ei[e];
    int dst = ei[NE + e];
    int rel = et[e];
    int b = dst >> 5;
    unsigned int rec = (unsigned int)src | ((unsigned int)rel << 17) |
                       ((unsigned int)(dst & 31) << 19);
    int cell = b * NXCD + p;
    int pos = atomicAdd(&bcnt[cell], 1);
    if (pos < PSTRIDE) arena[(size_t)cell * PSTRIDE + pos] = rec;
}

// ---------------- per-bucket LDS counting sort: 8 partitions -> sorted src + offsets ----------------
// key = dstlo*3 + rel (96 keys). Packed sorted writeback at bucket base (stride BSLOTS).
__global__ __launch_bounds__(256) void k_sortbucket(
        const int* __restrict__ bcnt, unsigned int* __restrict__ arena,
        unsigned short* __restrict__ off16) {
    __shared__ unsigned int s_rec[BSLOTS];
    __shared__ unsigned int s_srt[BSLOTS];
    __shared__ int s_hist[97], s_start[97], s_pos[96];
    int t = threadIdx.x;
    int b = blockIdx.x;

    if (t < 97) s_hist[t] = 0;
    __syncthreads();

    int tot = 0;
#pragma unroll
    for (int p = 0; p < NXCD; ++p) {
        int c = bcnt[b * NXCD + p]; if (c > PSTRIDE) c = PSTRIDE;
        const unsigned int* src = arena + ((size_t)(b * NXCD + p)) * PSTRIDE;
        for (int i = t; i < c; i += 256) {
            unsigned int r = src[i];
            s_rec[tot + i] = r;
            int key = ((r >> 19) & 31) * 3 + ((r >> 17) & 3);
            atomicAdd(&s_hist[key], 1);
        }
        tot += c;
    }
    __syncthreads();
    if (t == 0) {
        int run = 0;
#pragma unroll 8
        for (int k = 0; k < 96; ++k) { s_start[k] = run; run += s_hist[k]; }
        s_start[96] = run;                 // == tot
    }
    __syncthreads();
    if (t < 96) s_pos[t] = s_start[t];
    __syncthreads();
    for (int i = t; i < tot; i += 256) {
        unsigned int r = s_rec[i];
        int key = ((r >> 19) & 31) * 3 + ((r >> 17) & 3);
        int p = atomicAdd(&s_pos[key], 1);
        s_srt[p] = r & 0x1FFFF;            // keep src only
    }
    __syncthreads();
    for (int i = t; i < tot; i += 256)      // coalesced packed writeback at bucket base
        arena[(size_t)b * BSLOTS + i] = s_srt[i];
    if (t < 97) off16[(size_t)b * OSTRIDE + t] = (unsigned short)s_start[t];
}

// ---------------- per-(r,dst) mean aggregation: wave per node ----------------
// Fused loop over the node's sorted edge range; relation by boundary compare.
// Writes K[v][0:64)=mean_r0, [64:128)=mean_r1, [128:192)=mean_r2, [192:256)=x[v]
__global__ void k_agg(const float* __restrict__ xin, const unsigned int* __restrict__ arena,
                      const unsigned short* __restrict__ off16, float* __restrict__ K) {
    int wid = (blockIdx.x * 256 + threadIdx.x) >> 6;
    int lane = threadIdx.x & 63;
    if (wid >= NN) return;
    int v = wid;
    int b = v >> 5, dlo = v & 31;
    const unsigned short* ofs = off16 + (size_t)b * OSTRIDE + dlo * 3;
    int s0 = __builtin_amdgcn_readfirstlane((int)ofs[0]);
    int s1 = __builtin_amdgcn_readfirstlane((int)ofs[1]);
    int s2 = __builtin_amdgcn_readfirstlane((int)ofs[2]);
    int s3 = __builtin_amdgcn_readfirstlane((int)ofs[3]);
    const unsigned int* base = arena + (size_t)b * BSLOTS;

    float a0 = 0.f, a1 = 0.f, a2 = 0.f;
    int e = s0;
    for (; e + 8 <= s3; e += 8) {
#pragma unroll
        for (int k = 0; k < 8; ++k) {
            int ee = e + k;
            int idx = (int)base[ee];                  // uniform -> s_load
            float x = xin[(size_t)idx * 64 + lane];   // coalesced 256B gather
            a0 += (ee < s1) ? x : 0.f;
            a1 += (ee >= s1 && ee < s2) ? x : 0.f;
            a2 += (ee >= s2) ? x : 0.f;
        }
    }
    for (; e < s3; ++e) {
        int idx = (int)base[e];
        float x = xin[(size_t)idx * 64 + lane];
        a0 += (e < s1) ? x : 0.f;
        a1 += (e >= s1 && e < s2) ? x : 0.f;
        a2 += (e >= s2) ? x : 0.f;
    }

    float* Kv = K + (size_t)v * 256;
    Kv[lane]       = a0 / fmaxf((float)(s1 - s0), 1.f);
    Kv[64 + lane]  = a1 / fmaxf((float)(s2 - s1), 1.f);
    Kv[128 + lane] = a2 / fmaxf((float)(s3 - s2), 1.f);
    Kv[192 + lane] = xin[(size_t)v * 64 + lane];
}

// ---------------- dense transform: xout = relu(K @ [Wr0;Wr1;Wr2;Wroot] + b) ----------------
// R8 shell (8 waves, wave owns 8 nodes, lane = h, K via scalar loads) with:
//  (1) K loaded as s_load_dwordx8 (f32x8 from readfirstlane-uniform base):
//      256 SMEM requests/wave instead of 512.
//  (2) W transposed in LDS [h][260] (row stride 260 = 4 mod 32 -> each 8-lane
//      group tiles all 32 banks -> conflict-free ds_read_b128): 2 b128/chunk
//      instead of 8 b32.
// Inner body per 8-d chunk: 8 s_load_dwordx8 + 2 ds_read_b128 + 64 pure FMAs.
__global__ __launch_bounds__(512, 4) void k_transform(
        const float* __restrict__ K, const float* __restrict__ wrel,
        const float* __restrict__ wroot, const float* __restrict__ b,
        float* __restrict__ xout) {
    __shared__ float s_wt[64][260];   // transposed: [h][d], rows 0..255 = wrel|wroot
    __shared__ float s_b[64];
    int t = threadIdx.x;
    for (int i = t; i < 192 * 64; i += 512) {      // global [d][h] -> s_wt[h][d]
        int d = i >> 6, h = i & 63;
        s_wt[h][d] = wrel[i];
    }
    for (int i = t; i < 64 * 64; i += 512) {
        int d = i >> 6, h = i & 63;
        s_wt[h][192 + d] = wroot[i];
    }
    if (t < 64) s_b[t] = b[t];
    __syncthreads();

    int wave = t >> 6, lane = t & 63;
    int v0 = blockIdx.x * 64 + wave * 8;   // 8 waves * 8 nodes = 64 nodes/block
    if (v0 >= NN) return;                   // NN % 8 == 0: active waves fully valid

    int v0u = __builtin_amdgcn_readfirstlane(v0);
    const float* Kb = K + (size_t)v0u * 256;   // uniform base -> scalar loads

    float acc[8];
    float bb = s_b[lane];
#pragma unroll
    for (int n = 0; n < 8; ++n) acc[n] = bb;

#pragma unroll 1
    for (int c = 0; c < 32; ++c) {             // 32 chunks of 8 d
        f32x8 k0 = *reinterpret_cast<const f32x8*>(Kb + 0 * 256 + c * 8);
        f32x8 k1 = *reinterpret_cast<const f32x8*>(Kb + 1 * 256 + c * 8);
        f32x8 k2 = *reinterpret_cast<const f32x8*>(Kb + 2 * 256 + c * 8);
        f32x8 k3 = *reinterpret_cast<const f32x8*>(Kb + 3 * 256 + c * 8);
        f32x8 k4 = *reinterpret_cast<const f32x8*>(Kb + 4 * 256 + c * 8);
        f32x8 k5 = *reinterpret_cast<const f32x8*>(Kb + 5 * 256 + c * 8);
        f32x8 k6 = *reinterpret_cast<const f32x8*>(Kb + 6 * 256 + c * 8);
        f32x8 k7 = *reinterpret_cast<const f32x8*>(Kb + 7 * 256 + c * 8);
        float4 wa = *reinterpret_cast<const float4*>(&s_wt[lane][c * 8]);
        float4 wb = *reinterpret_cast<const float4*>(&s_wt[lane][c * 8 + 4]);
#define ACCUM(n, kn)                                                  \
        acc[n] += kn[0] * wa.x; acc[n] += kn[1] * wa.y;               \
        acc[n] += kn[2] * wa.z; acc[n] += kn[3] * wa.w;               \
        acc[n] += kn[4] * wb.x; acc[n] += kn[5] * wb.y;               \
        acc[n] += kn[6] * wb.z; acc[n] += kn[7] * wb.w;
        ACCUM(0, k0) ACCUM(1, k1) ACCUM(2, k2) ACCUM(3, k3)
        ACCUM(4, k4) ACCUM(5, k5) ACCUM(6, k6) ACCUM(7, k7)
#undef ACCUM
    }

#pragma unroll
    for (int n = 0; n < 8; ++n)
        xout[(size_t)(v0 + n) * 64 + lane] = fmaxf(acc[n], 0.f);
}

// ---------------- global mean pool: wave-segmented over sorted batch ----------------
#define POOL_CHUNK 32
__global__ void k_pool(const float* __restrict__ x, const int* __restrict__ batch,
                       float* __restrict__ psum, int* __restrict__ pcnt) {
    int gwid = (blockIdx.x * 256 + threadIdx.x) >> 6;
    int lane = threadIdx.x & 63;
    int v0 = gwid * POOL_CHUNK;
    if (v0 >= NN) return;
    int v1 = v0 + POOL_CHUNK; if (v1 > NN) v1 = NN;
    float acc = 0.f;
    int cnt = 0;
    int gcur = batch[v0];
    for (int v = v0; v < v1; ++v) {
        int g = batch[v];
        if (g != gcur) {
            atomicAdd(&psum[gcur * 64 + lane], acc);
            if (lane == 0) atomicAdd(&pcnt[gcur], cnt);
            acc = 0.f; cnt = 0; gcur = g;
        }
        acc += x[(size_t)v * 64 + lane];
        ++cnt;
    }
    atomicAdd(&psum[gcur * 64 + lane], acc);
    if (lane == 0) atomicAdd(&pcnt[gcur], cnt);
}

__global__ void k_cls(const float* __restrict__ psum, const int* __restrict__ pcnt,
                      const float* __restrict__ w, const float* __restrict__ b,
                      float* __restrict__ out) {
    int gid = blockIdx.x * 256 + threadIdx.x;
    if (gid >= NG * 10) return;
    int g = gid / 10, c = gid % 10;
    float inv = 1.f / fmaxf((float)pcnt[g], 1.f);
    float acc = 0.f;
#pragma unroll
    for (int d = 0; d < 64; ++d) acc += psum[g * 64 + d] * w[d * 10 + c];
    out[gid] = acc * inv + b[c];
}

extern "C" void kernel_launch(void* const* d_in, const int* in_sizes, int n_in,
                              void* d_out, int out_size, void* d_ws, size_t ws_size,
                              hipStream_t stream) {
    const int*   x_idx  = (const int*)d_in[0];
    const int*   ei     = (const int*)d_in[1];
    const int*   et     = (const int*)d_in[2];
    const int*   batch  = (const int*)d_in[3];
    const float* semb   = (const float*)d_in[4];
    const float* cemb   = (const float*)d_in[5];
    const float* lin0w  = (const float*)d_in[6];
    const float* lin0b  = (const float*)d_in[7];
    const float* r1wrel = (const float*)d_in[8];
    const float* r1wroot= (const float*)d_in[9];
    const float* r1b    = (const float*)d_in[10];
    const float* r2wrel = (const float*)d_in[11];
    const float* r2wroot= (const float*)d_in[12];
    const float* r2b    = (const float*)d_in[13];
    const float* clsw   = (const float*)d_in[14];
    const float* clsb   = (const float*)d_in[15];
    float* out = (float*)d_out;

    char* ws = (char*)d_ws;
    size_t o = 0;
    auto alloc = [&](size_t bytes) -> void* {
        void* p = ws + o;
        o += (bytes + 255) & ~(size_t)255;
        return p;
    };
    int*            bcnt  = (int*)           alloc((size_t)NBUCK * NXCD * 4);
    unsigned int*   arena = (unsigned int*)  alloc((size_t)NBUCK * BSLOTS * 4);
    unsigned short* off16 = (unsigned short*)alloc((size_t)NBUCK * OSTRIDE * 2);
    float*          xA    = (float*)         alloc((size_t)NN * 64 * 4);
    float*          xB    = (float*)         alloc((size_t)NN * 64 * 4);
    float*          Kbuf  = (float*)         alloc((size_t)NN * 256 * 4);
    float*          psum  = (float*)         alloc((size_t)NG * 64 * 4);
    int*            pcnt  = (int*)           alloc((size_t)NG * 4);

    hipMemsetAsync(bcnt, 0, (size_t)NBUCK * NXCD * 4, stream);
    hipMemsetAsync(psum, 0, (size_t)NG * 64 * 4, stream);
    hipMemsetAsync(pcnt, 0, (size_t)NG * 4, stream);

    // node features
    k_embed<<<NN * 64 / 256, 256, 0, stream>>>(x_idx, semb, cemb, lin0w, lin0b, xA);

    // bucket build (XCD-private) + per-bucket counting sort (once, reused by both layers)
    k_bucket<<<NE / 256, 256, 0, stream>>>(ei, et, bcnt, arena);
    k_sortbucket<<<NBUCK, 256, 0, stream>>>(bcnt, arena, off16);

    // layer 1
    k_agg<<<NN / 4, 256, 0, stream>>>(xA, arena, off16, Kbuf);
    k_transform<<<(NN + 63) / 64, 512, 0, stream>>>(Kbuf, r1wrel, r1wroot, r1b, xB);
    // layer 2
    k_agg<<<NN / 4, 256, 0, stream>>>(xB, arena, off16, Kbuf);
    k_transform<<<(NN + 63) / 64, 512, 0, stream>>>(Kbuf, r2wrel, r2wroot, r2b, xA);

    // pool + classify
    {
        int nwaves = (NN + POOL_CHUNK - 1) / POOL_CHUNK;        // 3125
        int nblk = (nwaves * 64 + 255) / 256;                   // 782
        k_pool<<<nblk, 256, 0, stream>>>(xA, batch, psum, pcnt);
    }
    k_cls<<<(NG * 10 + 255) / 256, 256, 0, stream>>>(psum, pcnt, clsw, clsb, out);
}

// Round 12
// 493.446 us; speedup vs baseline: 1.4904x; 1.0180x over previous
//
#include <hip/hip_runtime.h>

#define NN 100000        // nodes
#define NE 1600000       // edges
#define NRL 3            // relations
#define NG 1024          // graphs
#define NBUCK 3125       // NN/32 buckets of 32 nodes
#define NXCD 8
#define PSTRIDE 128      // slots per (bucket, xcd): mean 64, sigma 8 -> +8 sigma
#define BSLOTS (NXCD * PSTRIDE)   // 1024 slots per bucket
#define OSTRIDE 104      // u16 offsets per bucket (96 starts + total, padded)

__device__ __forceinline__ int xcd_id() {
    unsigned int x;
    asm volatile("s_getreg_b32 %0, hwreg(HW_REG_XCC_ID)" : "=s"(x));
    return (int)(x & 7);
}

// f32 -> bf16 with round-to-nearest-even
__device__ __forceinline__ unsigned short f2bf(float f) {
    unsigned u = __float_as_uint(f);
    unsigned r = (u + 0x7fffu + ((u >> 16) & 1u)) >> 16;
    return (unsigned short)r;
}

// ---------------- embed + lin0 + relu ----------------
__global__ void k_embed(const int* __restrict__ x_idx,
                        const float* __restrict__ semb, const float* __restrict__ cemb,
                        const float* __restrict__ w, const float* __restrict__ b,
                        float* __restrict__ xout) {
    __shared__ float s_w[16 * 64];
    __shared__ float s_se[64], s_ce[64], s_b[64];
    int t = threadIdx.x;
    for (int i = t; i < 16 * 64; i += 256) s_w[i] = w[i];
    if (t < 64) { s_se[t] = semb[t]; s_ce[t] = cemb[t]; s_b[t] = b[t]; }
    __syncthreads();
    int gid = blockIdx.x * 256 + t;           // grid exactly NN*64/256
    int v = gid >> 6, h = gid & 63;
    int si = x_idx[2 * v], ci = x_idx[2 * v + 1];
    float acc = s_b[h];
#pragma unroll
    for (int d = 0; d < 8; ++d) acc += s_se[si * 8 + d] * s_w[d * 64 + h];
#pragma unroll
    for (int d = 0; d < 8; ++d) acc += s_ce[ci * 8 + d] * s_w[(8 + d) * 64 + h];
    xout[gid] = fmaxf(acc, 0.f);
}

// ---------------- bucket build: XCD-private append of packed edge records ----------------
// rec = src (17b) | rel<<17 (2b) | (dst&31)<<19 (5b)
__global__ void k_bucket(const int* __restrict__ ei, const int* __restrict__ et,
                         int* __restrict__ bcnt, unsigned int* __restrict__ arena) {
    int e = blockIdx.x * 256 + threadIdx.x;
    if (e >= NE) return;
    int p = xcd_id();                          // wave-uniform physical XCD
    int src = ei[e];
    int dst = ei[NE + e];
    int rel = et[e];
    int b = dst >> 5;
    unsigned int rec = (unsigned int)src | ((unsigned int)rel << 17) |
                       ((unsigned int)(dst & 31) << 19);
    int cell = b * NXCD + p;
    int pos = atomicAdd(&bcnt[cell], 1);
    if (pos < PSTRIDE) arena[(size_t)cell * PSTRIDE + pos] = rec;
}

// ---------------- per-bucket LDS counting sort: 8 partitions -> sorted src + offsets ----------------
// key = dstlo*3 + rel (96 keys). Packed sorted writeback at bucket base (stride BSLOTS).
__global__ __launch_bounds__(256) void k_sortbucket(
        const int* __restrict__ bcnt, unsigned int* __restrict__ arena,
        unsigned short* __restrict__ off16) {
    __shared__ unsigned int s_rec[BSLOTS];
    __shared__ unsigned int s_srt[BSLOTS];
    __shared__ int s_hist[97], s_start[97], s_pos[96];
    int t = threadIdx.x;
    int b = blockIdx.x;

    if (t < 97) s_hist[t] = 0;
    __syncthreads();

    int tot = 0;
#pragma unroll
    for (int p = 0; p < NXCD; ++p) {
        int c = bcnt[b * NXCD + p]; if (c > PSTRIDE) c = PSTRIDE;
        const unsigned int* src = arena + ((size_t)(b * NXCD + p)) * PSTRIDE;
        for (int i = t; i < c; i += 256) {
            unsigned int r = src[i];
            s_rec[tot + i] = r;
            int key = ((r >> 19) & 31) * 3 + ((r >> 17) & 3);
            atomicAdd(&s_hist[key], 1);
        }
        tot += c;
    }
    __syncthreads();
    if (t == 0) {
        int run = 0;
#pragma unroll 8
        for (int k = 0; k < 96; ++k) { s_start[k] = run; run += s_hist[k]; }
        s_start[96] = run;                 // == tot
    }
    __syncthreads();
    if (t < 96) s_pos[t] = s_start[t];
    __syncthreads();
    for (int i = t; i < tot; i += 256) {
        unsigned int r = s_rec[i];
        int key = ((r >> 19) & 31) * 3 + ((r >> 17) & 3);
        int p = atomicAdd(&s_pos[key], 1);
        s_srt[p] = r & 0x1FFFF;            // keep src only
    }
    __syncthreads();
    for (int i = t; i < tot; i += 256)      // coalesced packed writeback at bucket base
        arena[(size_t)b * BSLOTS + i] = s_srt[i];
    if (t < 97) off16[(size_t)b * OSTRIDE + t] = (unsigned short)s_start[t];
}

// ---------------- per-(r,dst) mean aggregation: wave per node ----------------
// Fused loop over the node's sorted edge range; relation by boundary compare.
// Writes bf16 K[v][0:64)=mean_r0, [64:128)=mean_r1, [128:192)=mean_r2, [192:256)=x[v]
__global__ void k_agg(const float* __restrict__ xin, const unsigned int* __restrict__ arena,
                      const unsigned short* __restrict__ off16,
                      unsigned short* __restrict__ K) {
    int wid = (blockIdx.x * 256 + threadIdx.x) >> 6;
    int lane = threadIdx.x & 63;
    if (wid >= NN) return;
    int v = wid;
    int b = v >> 5, dlo = v & 31;
    const unsigned short* ofs = off16 + (size_t)b * OSTRIDE + dlo * 3;
    int s0 = __builtin_amdgcn_readfirstlane((int)ofs[0]);
    int s1 = __builtin_amdgcn_readfirstlane((int)ofs[1]);
    int s2 = __builtin_amdgcn_readfirstlane((int)ofs[2]);
    int s3 = __builtin_amdgcn_readfirstlane((int)ofs[3]);
    const unsigned int* base = arena + (size_t)b * BSLOTS;

    float a0 = 0.f, a1 = 0.f, a2 = 0.f;
    int e = s0;
    for (; e + 8 <= s3; e += 8) {
#pragma unroll
        for (int k = 0; k < 8; ++k) {
            int ee = e + k;
            int idx = (int)base[ee];                  // uniform -> s_load
            float x = xin[(size_t)idx * 64 + lane];   // coalesced 256B gather
            a0 += (ee < s1) ? x : 0.f;
            a1 += (ee >= s1 && ee < s2) ? x : 0.f;
            a2 += (ee >= s2) ? x : 0.f;
        }
    }
    for (; e < s3; ++e) {
        int idx = (int)base[e];
        float x = xin[(size_t)idx * 64 + lane];
        a0 += (e < s1) ? x : 0.f;
        a1 += (e >= s1 && e < s2) ? x : 0.f;
        a2 += (e >= s2) ? x : 0.f;
    }

    unsigned short* Kv = K + (size_t)v * 256;
    Kv[lane]       = f2bf(a0 / fmaxf((float)(s1 - s0), 1.f));   // 2B/lane, coalesced
    Kv[64 + lane]  = f2bf(a1 / fmaxf((float)(s2 - s1), 1.f));
    Kv[128 + lane] = f2bf(a2 / fmaxf((float)(s3 - s2), 1.f));
    Kv[192 + lane] = f2bf(xin[(size_t)v * 64 + lane]);
}

// ---------------- dense transform: xout = relu(K @ [Wr0;Wr1;Wr2;Wroot] + b) ----------------
// R8 shell (8 waves, wave owns 8 nodes, lane = h). K is bf16: HALF the scalar-path
// bytes. Per node per 8-d chunk: one s_load_dwordx4 (4 u32 = 8 bf16); unpack on the
// SCALAR pipe (s_lshl / s_and: f32(2j)=u<<16, f32(2j+1)=u&0xFFFF0000); FMA takes the
// K scalar as its SGPR operand. W in LDS [d][h] (R8 layout, conflict-free).
__global__ __launch_bounds__(512, 4) void k_transform(
        const unsigned int* __restrict__ K, const float* __restrict__ wrel,
        const float* __restrict__ wroot, const float* __restrict__ b,
        float* __restrict__ xout) {
    __shared__ float s_w[256 * 64];   // rows 0..191 = wrel, rows 192..255 = wroot
    __shared__ float s_b[64];
    int t = threadIdx.x;
    for (int i = t; i < 192 * 64; i += 512) s_w[i] = wrel[i];
    for (int i = t; i < 64 * 64; i += 512) s_w[192 * 64 + i] = wroot[i];
    if (t < 64) s_b[t] = b[t];
    __syncthreads();

    int wave = t >> 6, lane = t & 63;
    int v0 = blockIdx.x * 64 + wave * 8;   // 8 waves * 8 nodes = 64 nodes/block
    if (v0 >= NN) return;                   // NN % 8 == 0: active waves fully valid

    int v0u = __builtin_amdgcn_readfirstlane(v0);
    const unsigned int* Kb = K + (size_t)v0u * 128;   // 128 u32 (256 bf16) per node

    float acc[8];
    float bb = s_b[lane];
#pragma unroll
    for (int n = 0; n < 8; ++n) acc[n] = bb;

#pragma unroll 2
    for (int c = 0; c < 32; ++c) {             // 32 chunks of 8 d
        float w0 = s_w[(c * 8 + 0) * 64 + lane];
        float w1 = s_w[(c * 8 + 1) * 64 + lane];
        float w2 = s_w[(c * 8 + 2) * 64 + lane];
        float w3 = s_w[(c * 8 + 3) * 64 + lane];
        float w4 = s_w[(c * 8 + 4) * 64 + lane];
        float w5 = s_w[(c * 8 + 5) * 64 + lane];
        float w6 = s_w[(c * 8 + 6) * 64 + lane];
        float w7 = s_w[(c * 8 + 7) * 64 + lane];
#pragma unroll
        for (int n = 0; n < 8; ++n) {
            uint4 kw = *reinterpret_cast<const uint4*>(Kb + n * 128 + c * 4); // s_load_dwordx4
            float k0 = __uint_as_float(kw.x << 16);
            float k1 = __uint_as_float(kw.x & 0xFFFF0000u);
            float k2 = __uint_as_float(kw.y << 16);
            float k3 = __uint_as_float(kw.y & 0xFFFF0000u);
            float k4 = __uint_as_float(kw.z << 16);
            float k5 = __uint_as_float(kw.z & 0xFFFF0000u);
            float k6 = __uint_as_float(kw.w << 16);
            float k7 = __uint_as_float(kw.w & 0xFFFF0000u);
            acc[n] += k0 * w0;
            acc[n] += k1 * w1;
            acc[n] += k2 * w2;
            acc[n] += k3 * w3;
            acc[n] += k4 * w4;
            acc[n] += k5 * w5;
            acc[n] += k6 * w6;
            acc[n] += k7 * w7;
        }
    }

#pragma unroll
    for (int n = 0; n < 8; ++n)
        xout[(size_t)(v0 + n) * 64 + lane] = fmaxf(acc[n], 0.f);
}

// ---------------- global mean pool: wave-segmented over sorted batch ----------------
#define POOL_CHUNK 32
__global__ void k_pool(const float* __restrict__ x, const int* __restrict__ batch,
                       float* __restrict__ psum, int* __restrict__ pcnt) {
    int gwid = (blockIdx.x * 256 + threadIdx.x) >> 6;
    int lane = threadIdx.x & 63;
    int v0 = gwid * POOL_CHUNK;
    if (v0 >= NN) return;
    int v1 = v0 + POOL_CHUNK; if (v1 > NN) v1 = NN;
    float acc = 0.f;
    int cnt = 0;
    int gcur = batch[v0];
    for (int v = v0; v < v1; ++v) {
        int g = batch[v];
        if (g != gcur) {
            atomicAdd(&psum[gcur * 64 + lane], acc);
            if (lane == 0) atomicAdd(&pcnt[gcur], cnt);
            acc = 0.f; cnt = 0; gcur = g;
        }
        acc += x[(size_t)v * 64 + lane];
        ++cnt;
    }
    atomicAdd(&psum[gcur * 64 + lane], acc);
    if (lane == 0) atomicAdd(&pcnt[gcur], cnt);
}

__global__ void k_cls(const float* __restrict__ psum, const int* __restrict__ pcnt,
                      const float* __restrict__ w, const float* __restrict__ b,
                      float* __restrict__ out) {
    int gid = blockIdx.x * 256 + threadIdx.x;
    if (gid >= NG * 10) return;
    int g = gid / 10, c = gid % 10;
    float inv = 1.f / fmaxf((float)pcnt[g], 1.f);
    float acc = 0.f;
#pragma unroll
    for (int d = 0; d < 64; ++d) acc += psum[g * 64 + d] * w[d * 10 + c];
    out[gid] = acc * inv + b[c];
}

extern "C" void kernel_launch(void* const* d_in, const int* in_sizes, int n_in,
                              void* d_out, int out_size, void* d_ws, size_t ws_size,
                              hipStream_t stream) {
    const int*   x_idx  = (const int*)d_in[0];
    const int*   ei     = (const int*)d_in[1];
    const int*   et     = (const int*)d_in[2];
    const int*   batch  = (const int*)d_in[3];
    const float* semb   = (const float*)d_in[4];
    const float* cemb   = (const float*)d_in[5];
    const float* lin0w  = (const float*)d_in[6];
    const float* lin0b  = (const float*)d_in[7];
    const float* r1wrel = (const float*)d_in[8];
    const float* r1wroot= (const float*)d_in[9];
    const float* r1b    = (const float*)d_in[10];
    const float* r2wrel = (const float*)d_in[11];
    const float* r2wroot= (const float*)d_in[12];
    const float* r2b    = (const float*)d_in[13];
    const float* clsw   = (const float*)d_in[14];
    const float* clsb   = (const float*)d_in[15];
    float* out = (float*)d_out;

    char* ws = (char*)d_ws;
    size_t o = 0;
    auto alloc = [&](size_t bytes) -> void* {
        void* p = ws + o;
        o += (bytes + 255) & ~(size_t)255;
        return p;
    };
    int*            bcnt  = (int*)           alloc((size_t)NBUCK * NXCD * 4);
    unsigned int*   arena = (unsigned int*)  alloc((size_t)NBUCK * BSLOTS * 4);
    unsigned short* off16 = (unsigned short*)alloc((size_t)NBUCK * OSTRIDE * 2);
    float*          xA    = (float*)         alloc((size_t)NN * 64 * 4);
    float*          xB    = (float*)         alloc((size_t)NN * 64 * 4);
    unsigned short* Kbuf  = (unsigned short*)alloc((size_t)NN * 256 * 2);   // bf16
    float*          psum  = (float*)         alloc((size_t)NG * 64 * 4);
    int*            pcnt  = (int*)           alloc((size_t)NG * 4);

    hipMemsetAsync(bcnt, 0, (size_t)NBUCK * NXCD * 4, stream);
    hipMemsetAsync(psum, 0, (size_t)NG * 64 * 4, stream);
    hipMemsetAsync(pcnt, 0, (size_t)NG * 4, stream);

    // node features
    k_embed<<<NN * 64 / 256, 256, 0, stream>>>(x_idx, semb, cemb, lin0w, lin0b, xA);

    // bucket build (XCD-private) + per-bucket counting sort (once, reused by both layers)
    k_bucket<<<NE / 256, 256, 0, stream>>>(ei, et, bcnt, arena);
    k_sortbucket<<<NBUCK, 256, 0, stream>>>(bcnt, arena, off16);

    // layer 1
    k_agg<<<NN / 4, 256, 0, stream>>>(xA, arena, off16, Kbuf);
    k_transform<<<(NN + 63) / 64, 512, 0, stream>>>((const unsigned int*)Kbuf,
                                                    r1wrel, r1wroot, r1b, xB);
    // layer 2
    k_agg<<<NN / 4, 256, 0, stream>>>(xB, arena, off16, Kbuf);
    k_transform<<<(NN + 63) / 64, 512, 0, stream>>>((const unsigned int*)Kbuf,
                                                    r2wrel, r2wroot, r2b, xA);

    // pool + classify
    {
        int nwaves = (NN + POOL_CHUNK - 1) / POOL_CHUNK;        // 3125
        int nblk = (nwaves * 64 + 255) / 256;                   // 782
        k_pool<<<nblk, 256, 0, stream>>>(xA, batch, psum, pcnt);
    }
    k_cls<<<(NG * 10 + 255) / 256, 256, 0, stream>>>(psum, pcnt, clsw, clsb, out);
}

// Round 13
// 358.916 us; speedup vs baseline: 2.0491x; 1.3748x over previous
//
#include <hip/hip_runtime.h>

#define NN 100000        // nodes
#define NE 1600000       // edges
#define NRL 3            // relations
#define NG 1024          // graphs
#define NBUCK 3125       // NN/32 buckets of 32 nodes
#define NXCD 8
#define PSTRIDE 128      // slots per (bucket, xcd): mean 64, sigma 8 -> +8 sigma
#define BSLOTS (NXCD * PSTRIDE)   // 1024 slots per bucket
#define OSTRIDE 104      // u16 offsets per bucket (96 starts + total, padded)

typedef __attribute__((ext_vector_type(8))) short bf16x8;
typedef __attribute__((ext_vector_type(4))) float f32x4;

__device__ __forceinline__ int xcd_id() {
    unsigned int x;
    asm volatile("s_getreg_b32 %0, hwreg(HW_REG_XCC_ID)" : "=s"(x));
    return (int)(x & 7);
}

// f32 -> bf16 with round-to-nearest-even
__device__ __forceinline__ unsigned short f2bf(float f) {
    unsigned u = __float_as_uint(f);
    unsigned r = (u + 0x7fffu + ((u >> 16) & 1u)) >> 16;
    return (unsigned short)r;
}

// ---------------- embed + lin0 + relu ----------------
__global__ void k_embed(const int* __restrict__ x_idx,
                        const float* __restrict__ semb, const float* __restrict__ cemb,
                        const float* __restrict__ w, const float* __restrict__ b,
                        float* __restrict__ xout) {
    __shared__ float s_w[16 * 64];
    __shared__ float s_se[64], s_ce[64], s_b[64];
    int t = threadIdx.x;
    for (int i = t; i < 16 * 64; i += 256) s_w[i] = w[i];
    if (t < 64) { s_se[t] = semb[t]; s_ce[t] = cemb[t]; s_b[t] = b[t]; }
    __syncthreads();
    int gid = blockIdx.x * 256 + t;           // grid exactly NN*64/256
    int v = gid >> 6, h = gid & 63;
    int si = x_idx[2 * v], ci = x_idx[2 * v + 1];
    float acc = s_b[h];
#pragma unroll
    for (int d = 0; d < 8; ++d) acc += s_se[si * 8 + d] * s_w[d * 64 + h];
#pragma unroll
    for (int d = 0; d < 8; ++d) acc += s_ce[ci * 8 + d] * s_w[(8 + d) * 64 + h];
    xout[gid] = fmaxf(acc, 0.f);
}

// ---------------- bucket build: XCD-private append of packed edge records ----------------
// rec = src (17b) | rel<<17 (2b) | (dst&31)<<19 (5b)
__global__ void k_bucket(const int* __restrict__ ei, const int* __restrict__ et,
                         int* __restrict__ bcnt, unsigned int* __restrict__ arena) {
    int e = blockIdx.x * 256 + threadIdx.x;
    if (e >= NE) return;
    int p = xcd_id();                          // wave-uniform physical XCD
    int src = ei[e];
    int dst = ei[NE + e];
    int rel = et[e];
    int b = dst >> 5;
    unsigned int rec = (unsigned int)src | ((unsigned int)rel << 17) |
                       ((unsigned int)(dst & 31) << 19);
    int cell = b * NXCD + p;
    int pos = atomicAdd(&bcnt[cell], 1);
    if (pos < PSTRIDE) arena[(size_t)cell * PSTRIDE + pos] = rec;
}

// ---------------- per-bucket LDS counting sort: 8 partitions -> sorted src + offsets ----------------
// key = dstlo*3 + rel (96 keys). Packed sorted writeback at bucket base (stride BSLOTS).
__global__ __launch_bounds__(256) void k_sortbucket(
        const int* __restrict__ bcnt, unsigned int* __restrict__ arena,
        unsigned short* __restrict__ off16) {
    __shared__ unsigned int s_rec[BSLOTS];
    __shared__ unsigned int s_srt[BSLOTS];
    __shared__ int s_hist[97], s_start[97], s_pos[96];
    int t = threadIdx.x;
    int b = blockIdx.x;

    if (t < 97) s_hist[t] = 0;
    __syncthreads();

    int tot = 0;
#pragma unroll
    for (int p = 0; p < NXCD; ++p) {
        int c = bcnt[b * NXCD + p]; if (c > PSTRIDE) c = PSTRIDE;
        const unsigned int* src = arena + ((size_t)(b * NXCD + p)) * PSTRIDE;
        for (int i = t; i < c; i += 256) {
            unsigned int r = src[i];
            s_rec[tot + i] = r;
            int key = ((r >> 19) & 31) * 3 + ((r >> 17) & 3);
            atomicAdd(&s_hist[key], 1);
        }
        tot += c;
    }
    __syncthreads();
    if (t == 0) {
        int run = 0;
#pragma unroll 8
        for (int k = 0; k < 96; ++k) { s_start[k] = run; run += s_hist[k]; }
        s_start[96] = run;                 // == tot
    }
    __syncthreads();
    if (t < 96) s_pos[t] = s_start[t];
    __syncthreads();
    for (int i = t; i < tot; i += 256) {
        unsigned int r = s_rec[i];
        int key = ((r >> 19) & 31) * 3 + ((r >> 17) & 3);
        int p = atomicAdd(&s_pos[key], 1);
        s_srt[p] = r & 0x1FFFF;            // keep src only
    }
    __syncthreads();
    for (int i = t; i < tot; i += 256)      // coalesced packed writeback at bucket base
        arena[(size_t)b * BSLOTS + i] = s_srt[i];
    if (t < 97) off16[(size_t)b * OSTRIDE + t] = (unsigned short)s_start[t];
}

// ---------------- per-(r,dst) mean aggregation: wave per node ----------------
// Fused loop over the node's sorted edge range; relation by boundary compare.
// Writes bf16 K[v][0:64)=mean_r0, [64:128)=mean_r1, [128:192)=mean_r2, [192:256)=x[v]
__global__ void k_agg(const float* __restrict__ xin, const unsigned int* __restrict__ arena,
                      const unsigned short* __restrict__ off16,
                      unsigned short* __restrict__ K) {
    int wid = (blockIdx.x * 256 + threadIdx.x) >> 6;
    int lane = threadIdx.x & 63;
    if (wid >= NN) return;
    int v = wid;
    int b = v >> 5, dlo = v & 31;
    const unsigned short* ofs = off16 + (size_t)b * OSTRIDE + dlo * 3;
    int s0 = __builtin_amdgcn_readfirstlane((int)ofs[0]);
    int s1 = __builtin_amdgcn_readfirstlane((int)ofs[1]);
    int s2 = __builtin_amdgcn_readfirstlane((int)ofs[2]);
    int s3 = __builtin_amdgcn_readfirstlane((int)ofs[3]);
    const unsigned int* base = arena + (size_t)b * BSLOTS;

    float a0 = 0.f, a1 = 0.f, a2 = 0.f;
    int e = s0;
    for (; e + 8 <= s3; e += 8) {
#pragma unroll
        for (int k = 0; k < 8; ++k) {
            int ee = e + k;
            int idx = (int)base[ee];                  // uniform -> s_load
            float x = xin[(size_t)idx * 64 + lane];   // coalesced 256B gather
            a0 += (ee < s1) ? x : 0.f;
            a1 += (ee >= s1 && ee < s2) ? x : 0.f;
            a2 += (ee >= s2) ? x : 0.f;
        }
    }
    for (; e < s3; ++e) {
        int idx = (int)base[e];
        float x = xin[(size_t)idx * 64 + lane];
        a0 += (e < s1) ? x : 0.f;
        a1 += (e >= s1 && e < s2) ? x : 0.f;
        a2 += (e >= s2) ? x : 0.f;
    }

    unsigned short* Kv = K + (size_t)v * 256;
    Kv[lane]       = f2bf(a0 / fmaxf((float)(s1 - s0), 1.f));   // 2B/lane, coalesced
    Kv[64 + lane]  = f2bf(a1 / fmaxf((float)(s2 - s1), 1.f));
    Kv[128 + lane] = f2bf(a2 / fmaxf((float)(s3 - s2), 1.f));
    Kv[192 + lane] = f2bf(xin[(size_t)v * 64 + lane]);
}

// ---------------- dense transform via MFMA: xout = relu(K @ [Wr;Wroot] + b) ----------------
// v_mfma_f32_16x16x32_bf16. Wave = 16-node strip x 64 h (4 C-tiles). 8 K-iters of 32.
// A frag: lane l loads 8 contiguous bf16 of K[(v0+(l&15))*256 + c*32 + (l>>4)*8] (16B vector load).
// B frag: W cast to bf16, staged in LDS in FRAG ORDER with the SAME k-map (g*8+j) as A
//   -> correctness independent of the HW's internal k-order (A/B slots pair by (g,j)).
// C/D layout (m89-verified): col = lane&15, row = (lane>>4)*4 + reg.
__global__ __launch_bounds__(512, 4) void k_transform(
        const unsigned short* __restrict__ K, const float* __restrict__ wrel,
        const float* __restrict__ wroot, const float* __restrict__ b,
        float* __restrict__ xout) {
    __shared__ __align__(16) unsigned short s_bf[4][8][64][8];  // [ntile][kiter][lane][j]
    __shared__ float s_b[64];
    int t = threadIdx.x;
    for (int i = t; i < 4 * 8 * 64 * 8; i += 512) {
        int j  = i & 7;
        int l  = (i >> 3) & 63;
        int c  = (i >> 9) & 7;
        int nt = (i >> 12) & 3;
        int k  = c * 32 + (l >> 4) * 8 + j;     // same k-map as the A load below
        int n  = nt * 16 + (l & 15);
        const float* src = (k < 192) ? (wrel + k * 64 + n) : (wroot + (k - 192) * 64 + n);
        s_bf[nt][c][l][j] = f2bf(*src);
    }
    if (t < 64) s_b[t] = b[t];
    __syncthreads();

    int wave = t >> 6, lane = t & 63;
    int strip = blockIdx.x * 8 + wave;
    if (strip > NN / 16 - 1) strip = NN / 16 - 1;   // dup strips write identical data
    int v0 = strip * 16;

    const unsigned short* Ka = K + (size_t)(v0 + (lane & 15)) * 256 + (lane >> 4) * 8;

    f32x4 acc0 = {0.f, 0.f, 0.f, 0.f};
    f32x4 acc1 = {0.f, 0.f, 0.f, 0.f};
    f32x4 acc2 = {0.f, 0.f, 0.f, 0.f};
    f32x4 acc3 = {0.f, 0.f, 0.f, 0.f};

#pragma unroll
    for (int c = 0; c < 8; ++c) {
        bf16x8 a = *reinterpret_cast<const bf16x8*>(Ka + c * 32);
        bf16x8 b0 = *reinterpret_cast<const bf16x8*>(&s_bf[0][c][lane][0]);
        bf16x8 b1 = *reinterpret_cast<const bf16x8*>(&s_bf[1][c][lane][0]);
        bf16x8 b2 = *reinterpret_cast<const bf16x8*>(&s_bf[2][c][lane][0]);
        bf16x8 b3 = *reinterpret_cast<const bf16x8*>(&s_bf[3][c][lane][0]);
        acc0 = __builtin_amdgcn_mfma_f32_16x16x32_bf16(a, b0, acc0, 0, 0, 0);
        acc1 = __builtin_amdgcn_mfma_f32_16x16x32_bf16(a, b1, acc1, 0, 0, 0);
        acc2 = __builtin_amdgcn_mfma_f32_16x16x32_bf16(a, b2, acc2, 0, 0, 0);
        acc3 = __builtin_amdgcn_mfma_f32_16x16x32_bf16(a, b3, acc3, 0, 0, 0);
    }

    int col = lane & 15, rg = (lane >> 4) * 4;
#pragma unroll
    for (int r = 0; r < 4; ++r) {
        float* op = xout + (size_t)(v0 + rg + r) * 64;
        op[0  + col] = fmaxf(acc0[r] + s_b[0  + col], 0.f);
        op[16 + col] = fmaxf(acc1[r] + s_b[16 + col], 0.f);
        op[32 + col] = fmaxf(acc2[r] + s_b[32 + col], 0.f);
        op[48 + col] = fmaxf(acc3[r] + s_b[48 + col], 0.f);
    }
}

// ---------------- global mean pool: wave-segmented over sorted batch ----------------
#define POOL_CHUNK 32
__global__ void k_pool(const float* __restrict__ x, const int* __restrict__ batch,
                       float* __restrict__ psum, int* __restrict__ pcnt) {
    int gwid = (blockIdx.x * 256 + threadIdx.x) >> 6;
    int lane = threadIdx.x & 63;
    int v0 = gwid * POOL_CHUNK;
    if (v0 >= NN) return;
    int v1 = v0 + POOL_CHUNK; if (v1 > NN) v1 = NN;
    float acc = 0.f;
    int cnt = 0;
    int gcur = batch[v0];
    for (int v = v0; v < v1; ++v) {
        int g = batch[v];
        if (g != gcur) {
            atomicAdd(&psum[gcur * 64 + lane], acc);
            if (lane == 0) atomicAdd(&pcnt[gcur], cnt);
            acc = 0.f; cnt = 0; gcur = g;
        }
        acc += x[(size_t)v * 64 + lane];
        ++cnt;
    }
    atomicAdd(&psum[gcur * 64 + lane], acc);
    if (lane == 0) atomicAdd(&pcnt[gcur], cnt);
}

__global__ void k_cls(const float* __restrict__ psum, const int* __restrict__ pcnt,
                      const float* __restrict__ w, const float* __restrict__ b,
                      float* __restrict__ out) {
    int gid = blockIdx.x * 256 + threadIdx.x;
    if (gid >= NG * 10) return;
    int g = gid / 10, c = gid % 10;
    float inv = 1.f / fmaxf((float)pcnt[g], 1.f);
    float acc = 0.f;
#pragma unroll
    for (int d = 0; d < 64; ++d) acc += psum[g * 64 + d] * w[d * 10 + c];
    out[gid] = acc * inv + b[c];
}

extern "C" void kernel_launch(void* const* d_in, const int* in_sizes, int n_in,
                              void* d_out, int out_size, void* d_ws, size_t ws_size,
                              hipStream_t stream) {
    const int*   x_idx  = (const int*)d_in[0];
    const int*   ei     = (const int*)d_in[1];
    const int*   et     = (const int*)d_in[2];
    const int*   batch  = (const int*)d_in[3];
    const float* semb   = (const float*)d_in[4];
    const float* cemb   = (const float*)d_in[5];
    const float* lin0w  = (const float*)d_in[6];
    const float* lin0b  = (const float*)d_in[7];
    const float* r1wrel = (const float*)d_in[8];
    const float* r1wroot= (const float*)d_in[9];
    const float* r1b    = (const float*)d_in[10];
    const float* r2wrel = (const float*)d_in[11];
    const float* r2wroot= (const float*)d_in[12];
    const float* r2b    = (const float*)d_in[13];
    const float* clsw   = (const float*)d_in[14];
    const float* clsb   = (const float*)d_in[15];
    float* out = (float*)d_out;

    char* ws = (char*)d_ws;
    size_t o = 0;
    auto alloc = [&](size_t bytes) -> void* {
        void* p = ws + o;
        o += (bytes + 255) & ~(size_t)255;
        return p;
    };
    int*            bcnt  = (int*)           alloc((size_t)NBUCK * NXCD * 4);
    unsigned int*   arena = (unsigned int*)  alloc((size_t)NBUCK * BSLOTS * 4);
    unsigned short* off16 = (unsigned short*)alloc((size_t)NBUCK * OSTRIDE * 2);
    float*          xA    = (float*)         alloc((size_t)NN * 64 * 4);
    float*          xB    = (float*)         alloc((size_t)NN * 64 * 4);
    unsigned short* Kbuf  = (unsigned short*)alloc((size_t)NN * 256 * 2);   // bf16
    float*          psum  = (float*)         alloc((size_t)NG * 64 * 4);
    int*            pcnt  = (int*)           alloc((size_t)NG * 4);

    hipMemsetAsync(bcnt, 0, (size_t)NBUCK * NXCD * 4, stream);
    hipMemsetAsync(psum, 0, (size_t)NG * 64 * 4, stream);
    hipMemsetAsync(pcnt, 0, (size_t)NG * 4, stream);

    // node features
    k_embed<<<NN * 64 / 256, 256, 0, stream>>>(x_idx, semb, cemb, lin0w, lin0b, xA);

    // bucket build (XCD-private) + per-bucket counting sort (once, reused by both layers)
    k_bucket<<<NE / 256, 256, 0, stream>>>(ei, et, bcnt, arena);
    k_sortbucket<<<NBUCK, 256, 0, stream>>>(bcnt, arena, off16);

    // layer 1
    k_agg<<<NN / 4, 256, 0, stream>>>(xA, arena, off16, Kbuf);
    k_transform<<<(NN / 16 + 7) / 8, 512, 0, stream>>>(Kbuf, r1wrel, r1wroot, r1b, xB);
    // layer 2
    k_agg<<<NN / 4, 256, 0, stream>>>(xB, arena, off16, Kbuf);
    k_transform<<<(NN / 16 + 7) / 8, 512, 0, stream>>>(Kbuf, r2wrel, r2wroot, r2b, xA);

    // pool + classify
    {
        int nwaves = (NN + POOL_CHUNK - 1) / POOL_CHUNK;        // 3125
        int nblk = (nwaves * 64 + 255) / 256;                   // 782
        k_pool<<<nblk, 256, 0, stream>>>(xA, batch, psum, pcnt);
    }
    k_cls<<<(NG * 10 + 255) / 256, 256, 0, stream>>>(psum, pcnt, clsw, clsb, out);
}

// Round 14
// 351.736 us; speedup vs baseline: 2.0909x; 1.0204x over previous
//
#include <hip/hip_runtime.h>

#define NN 100000        // nodes
#define NE 1600000       // edges
#define NRL 3            // relations
#define NG 1024          // graphs
#define NBUCK 782        // ceil(NN/128) buckets of 128 nodes
#define NXCD 8
#define PSTRIDE 384      // slots per (bucket, xcd): mean 256, sigma 16 -> +8 sigma
#define BSLOTS (NXCD * PSTRIDE)   // 3072 slots per bucket
#define NKEY 384         // 128 nodes * 3 rel
#define OSTRIDE 392      // u16 offsets per bucket (384 starts + total, padded)

typedef __attribute__((ext_vector_type(8))) short bf16x8;
typedef __attribute__((ext_vector_type(4))) float f32x4;

__device__ __forceinline__ int xcd_id() {
    unsigned int x;
    asm volatile("s_getreg_b32 %0, hwreg(HW_REG_XCC_ID)" : "=s"(x));
    return (int)(x & 7);
}

// f32 -> bf16 with round-to-nearest-even
__device__ __forceinline__ unsigned short f2bf(float f) {
    unsigned u = __float_as_uint(f);
    unsigned r = (u + 0x7fffu + ((u >> 16) & 1u)) >> 16;
    return (unsigned short)r;
}
__device__ __forceinline__ float bf2f(unsigned short s) {
    return __uint_as_float(((unsigned)s) << 16);
}

// ---------------- embed + lin0 + relu (writes f32 x and bf16 mirror) ----------------
__global__ void k_embed(const int* __restrict__ x_idx,
                        const float* __restrict__ semb, const float* __restrict__ cemb,
                        const float* __restrict__ w, const float* __restrict__ b,
                        float* __restrict__ xout, unsigned short* __restrict__ xbf) {
    __shared__ float s_w[16 * 64];
    __shared__ float s_se[64], s_ce[64], s_b[64];
    int t = threadIdx.x;
    for (int i = t; i < 16 * 64; i += 256) s_w[i] = w[i];
    if (t < 64) { s_se[t] = semb[t]; s_ce[t] = cemb[t]; s_b[t] = b[t]; }
    __syncthreads();
    int gid = blockIdx.x * 256 + t;           // grid exactly NN*64/256
    int v = gid >> 6, h = gid & 63;
    int si = x_idx[2 * v], ci = x_idx[2 * v + 1];
    float acc = s_b[h];
#pragma unroll
    for (int d = 0; d < 8; ++d) acc += s_se[si * 8 + d] * s_w[d * 64 + h];
#pragma unroll
    for (int d = 0; d < 8; ++d) acc += s_ce[ci * 8 + d] * s_w[(8 + d) * 64 + h];
    float r = fmaxf(acc, 0.f);
    xout[gid] = r;
    xbf[gid] = f2bf(r);
}

// ---------------- bucket build: XCD-private append of packed edge records ----------------
// rec = src (17b) | rel<<17 (2b) | (dst&127)<<19 (7b)
__global__ void k_bucket(const int* __restrict__ ei, const int* __restrict__ et,
                         int* __restrict__ bcnt, unsigned int* __restrict__ arena) {
    int e = blockIdx.x * 256 + threadIdx.x;
    if (e >= NE) return;
    int p = xcd_id();                          // wave-uniform physical XCD
    int src = ei[e];
    int dst = ei[NE + e];
    int rel = et[e];
    int b = dst >> 7;
    unsigned int rec = (unsigned int)src | ((unsigned int)rel << 17) |
                       ((unsigned int)(dst & 127) << 19);
    int cell = b * NXCD + p;
    int pos = atomicAdd(&bcnt[cell], 1);
    if (pos < PSTRIDE) arena[(size_t)cell * PSTRIDE + pos] = rec;
}

// ---------------- per-bucket LDS counting sort: 8 partitions -> sorted src + offsets ----------------
// key = dstlo*3 + rel (384 keys). Packed sorted writeback at bucket base (stride BSLOTS).
__global__ __launch_bounds__(256) void k_sortbucket(
        const int* __restrict__ bcnt, unsigned int* __restrict__ arena,
        unsigned short* __restrict__ off16) {
    __shared__ unsigned int s_rec[BSLOTS];
    __shared__ unsigned int s_srt[BSLOTS];
    __shared__ int s_hist[NKEY + 1], s_start[NKEY + 1], s_pos[NKEY];
    int t = threadIdx.x;
    int b = blockIdx.x;

    for (int i = t; i < NKEY + 1; i += 256) s_hist[i] = 0;
    __syncthreads();

    int tot = 0;
#pragma unroll
    for (int p = 0; p < NXCD; ++p) {
        int c = bcnt[b * NXCD + p]; if (c > PSTRIDE) c = PSTRIDE;
        const unsigned int* src = arena + ((size_t)(b * NXCD + p)) * PSTRIDE;
        for (int i = t; i < c; i += 256) {
            unsigned int r = src[i];
            s_rec[tot + i] = r;
            int key = ((r >> 19) & 127) * 3 + ((r >> 17) & 3);
            atomicAdd(&s_hist[key], 1);
        }
        tot += c;
    }
    __syncthreads();
    if (t == 0) {
        int run = 0;
#pragma unroll 8
        for (int k = 0; k < NKEY; ++k) { s_start[k] = run; run += s_hist[k]; }
        s_start[NKEY] = run;                 // == tot
    }
    __syncthreads();
    for (int i = t; i < NKEY; i += 256) s_pos[i] = s_start[i];
    __syncthreads();
    for (int i = t; i < tot; i += 256) {
        unsigned int r = s_rec[i];
        int key = ((r >> 19) & 127) * 3 + ((r >> 17) & 3);
        int p = atomicAdd(&s_pos[key], 1);
        s_srt[p] = r & 0x1FFFF;            // keep src only
    }
    __syncthreads();
    for (int i = t; i < tot; i += 256)      // coalesced packed writeback at bucket base
        arena[(size_t)b * BSLOTS + i] = s_srt[i];
    for (int i = t; i < NKEY + 1; i += 256)
        off16[(size_t)b * OSTRIDE + i] = (unsigned short)s_start[i];
}

// ---------------- per-(r,dst) mean aggregation: wave per node ----------------
// Gathers NEIGHBORS from the bf16 mirror (128B/edge). Self-term copied from mirror
// (bit-identical to f2bf(f32 x)). Writes bf16 K rows: r0,r1,r2 means + self.
__global__ void k_agg(const unsigned short* __restrict__ xbf,
                      const unsigned int* __restrict__ arena,
                      const unsigned short* __restrict__ off16,
                      unsigned short* __restrict__ K) {
    int wid = (blockIdx.x * 256 + threadIdx.x) >> 6;
    int lane = threadIdx.x & 63;
    if (wid >= NN) return;
    int v = wid;
    int b = v >> 7, dlo = v & 127;
    const unsigned short* ofs = off16 + (size_t)b * OSTRIDE + dlo * 3;
    int s0 = __builtin_amdgcn_readfirstlane((int)ofs[0]);
    int s1 = __builtin_amdgcn_readfirstlane((int)ofs[1]);
    int s2 = __builtin_amdgcn_readfirstlane((int)ofs[2]);
    int s3 = __builtin_amdgcn_readfirstlane((int)ofs[3]);
    const unsigned int* base = arena + (size_t)b * BSLOTS;

    float a0 = 0.f, a1 = 0.f, a2 = 0.f;
    int e = s0;
    for (; e + 8 <= s3; e += 8) {
#pragma unroll
        for (int k = 0; k < 8; ++k) {
            int ee = e + k;
            int idx = (int)base[ee];                      // uniform -> s_load
            float x = bf2f(xbf[(size_t)idx * 64 + lane]); // coalesced 128B gather
            a0 += (ee < s1) ? x : 0.f;
            a1 += (ee >= s1 && ee < s2) ? x : 0.f;
            a2 += (ee >= s2) ? x : 0.f;
        }
    }
    for (; e < s3; ++e) {
        int idx = (int)base[e];
        float x = bf2f(xbf[(size_t)idx * 64 + lane]);
        a0 += (e < s1) ? x : 0.f;
        a1 += (e >= s1 && e < s2) ? x : 0.f;
        a2 += (e >= s2) ? x : 0.f;
    }

    unsigned short* Kv = K + (size_t)v * 256;
    Kv[lane]       = f2bf(a0 / fmaxf((float)(s1 - s0), 1.f));   // 2B/lane, coalesced
    Kv[64 + lane]  = f2bf(a1 / fmaxf((float)(s2 - s1), 1.f));
    Kv[128 + lane] = f2bf(a2 / fmaxf((float)(s3 - s2), 1.f));
    Kv[192 + lane] = xbf[(size_t)v * 64 + lane];                // exact copy
}

// ---------------- dense transform via MFMA: xout = relu(K @ [Wr;Wroot] + b) ----------------
// v_mfma_f32_16x16x32_bf16. Wave = 16-node strip x 64 h (4 C-tiles). 8 K-iters of 32.
// A frag from global bf16 K (16B vector load); B frag (bf16 W) staged in LDS in frag
// order with the SAME k-map as A. C/D layout (m89): col=lane&15, row=(lane>>4)*4+reg.
// Optionally writes the bf16 mirror for the next layer's agg.
__global__ __launch_bounds__(512, 4) void k_transform(
        const unsigned short* __restrict__ K, const float* __restrict__ wrel,
        const float* __restrict__ wroot, const float* __restrict__ b,
        float* __restrict__ xout, unsigned short* __restrict__ xbf) {
    __shared__ __align__(16) unsigned short s_bf[4][8][64][8];  // [ntile][kiter][lane][j]
    __shared__ float s_b[64];
    int t = threadIdx.x;
    for (int i = t; i < 4 * 8 * 64 * 8; i += 512) {
        int j  = i & 7;
        int l  = (i >> 3) & 63;
        int c  = (i >> 9) & 7;
        int nt = (i >> 12) & 3;
        int k  = c * 32 + (l >> 4) * 8 + j;     // same k-map as the A load below
        int n  = nt * 16 + (l & 15);
        const float* src = (k < 192) ? (wrel + k * 64 + n) : (wroot + (k - 192) * 64 + n);
        s_bf[nt][c][l][j] = f2bf(*src);
    }
    if (t < 64) s_b[t] = b[t];
    __syncthreads();

    int wave = t >> 6, lane = t & 63;
    int strip = blockIdx.x * 8 + wave;
    if (strip > NN / 16 - 1) strip = NN / 16 - 1;   // dup strips write identical data
    int v0 = strip * 16;

    const unsigned short* Ka = K + (size_t)(v0 + (lane & 15)) * 256 + (lane >> 4) * 8;

    f32x4 acc0 = {0.f, 0.f, 0.f, 0.f};
    f32x4 acc1 = {0.f, 0.f, 0.f, 0.f};
    f32x4 acc2 = {0.f, 0.f, 0.f, 0.f};
    f32x4 acc3 = {0.f, 0.f, 0.f, 0.f};

#pragma unroll
    for (int c = 0; c < 8; ++c) {
        bf16x8 a = *reinterpret_cast<const bf16x8*>(Ka + c * 32);
        bf16x8 b0 = *reinterpret_cast<const bf16x8*>(&s_bf[0][c][lane][0]);
        bf16x8 b1 = *reinterpret_cast<const bf16x8*>(&s_bf[1][c][lane][0]);
        bf16x8 b2 = *reinterpret_cast<const bf16x8*>(&s_bf[2][c][lane][0]);
        bf16x8 b3 = *reinterpret_cast<const bf16x8*>(&s_bf[3][c][lane][0]);
        acc0 = __builtin_amdgcn_mfma_f32_16x16x32_bf16(a, b0, acc0, 0, 0, 0);
        acc1 = __builtin_amdgcn_mfma_f32_16x16x32_bf16(a, b1, acc1, 0, 0, 0);
        acc2 = __builtin_amdgcn_mfma_f32_16x16x32_bf16(a, b2, acc2, 0, 0, 0);
        acc3 = __builtin_amdgcn_mfma_f32_16x16x32_bf16(a, b3, acc3, 0, 0, 0);
    }

    int col = lane & 15, rg = (lane >> 4) * 4;
#pragma unroll
    for (int r = 0; r < 4; ++r) {
        float o0 = fmaxf(acc0[r] + s_b[0  + col], 0.f);
        float o1 = fmaxf(acc1[r] + s_b[16 + col], 0.f);
        float o2 = fmaxf(acc2[r] + s_b[32 + col], 0.f);
        float o3 = fmaxf(acc3[r] + s_b[48 + col], 0.f);
        float* op = xout + (size_t)(v0 + rg + r) * 64;
        op[0  + col] = o0;
        op[16 + col] = o1;
        op[32 + col] = o2;
        op[48 + col] = o3;
        if (xbf) {
            unsigned short* ob = xbf + (size_t)(v0 + rg + r) * 64;
            ob[0  + col] = f2bf(o0);
            ob[16 + col] = f2bf(o1);
            ob[32 + col] = f2bf(o2);
            ob[48 + col] = f2bf(o3);
        }
    }
}

// ---------------- global mean pool: wave-segmented over sorted batch ----------------
#define POOL_CHUNK 32
__global__ void k_pool(const float* __restrict__ x, const int* __restrict__ batch,
                       float* __restrict__ psum, int* __restrict__ pcnt) {
    int gwid = (blockIdx.x * 256 + threadIdx.x) >> 6;
    int lane = threadIdx.x & 63;
    int v0 = gwid * POOL_CHUNK;
    if (v0 >= NN) return;
    int v1 = v0 + POOL_CHUNK; if (v1 > NN) v1 = NN;
    float acc = 0.f;
    int cnt = 0;
    int gcur = batch[v0];
    for (int v = v0; v < v1; ++v) {
        int g = batch[v];
        if (g != gcur) {
            atomicAdd(&psum[gcur * 64 + lane], acc);
            if (lane == 0) atomicAdd(&pcnt[gcur], cnt);
            acc = 0.f; cnt = 0; gcur = g;
        }
        acc += x[(size_t)v * 64 + lane];
        ++cnt;
    }
    atomicAdd(&psum[gcur * 64 + lane], acc);
    if (lane == 0) atomicAdd(&pcnt[gcur], cnt);
}

__global__ void k_cls(const float* __restrict__ psum, const int* __restrict__ pcnt,
                      const float* __restrict__ w, const float* __restrict__ b,
                      float* __restrict__ out) {
    int gid = blockIdx.x * 256 + threadIdx.x;
    if (gid >= NG * 10) return;
    int g = gid / 10, c = gid % 10;
    float inv = 1.f / fmaxf((float)pcnt[g], 1.f);
    float acc = 0.f;
#pragma unroll
    for (int d = 0; d < 64; ++d) acc += psum[g * 64 + d] * w[d * 10 + c];
    out[gid] = acc * inv + b[c];
}

extern "C" void kernel_launch(void* const* d_in, const int* in_sizes, int n_in,
                              void* d_out, int out_size, void* d_ws, size_t ws_size,
                              hipStream_t stream) {
    const int*   x_idx  = (const int*)d_in[0];
    const int*   ei     = (const int*)d_in[1];
    const int*   et     = (const int*)d_in[2];
    const int*   batch  = (const int*)d_in[3];
    const float* semb   = (const float*)d_in[4];
    const float* cemb   = (const float*)d_in[5];
    const float* lin0w  = (const float*)d_in[6];
    const float* lin0b  = (const float*)d_in[7];
    const float* r1wrel = (const float*)d_in[8];
    const float* r1wroot= (const float*)d_in[9];
    const float* r1b    = (const float*)d_in[10];
    const float* r2wrel = (const float*)d_in[11];
    const float* r2wroot= (const float*)d_in[12];
    const float* r2b    = (const float*)d_in[13];
    const float* clsw   = (const float*)d_in[14];
    const float* clsb   = (const float*)d_in[15];
    float* out = (float*)d_out;

    char* ws = (char*)d_ws;
    size_t o = 0;
    auto alloc = [&](size_t bytes) -> void* {
        void* p = ws + o;
        o += (bytes + 255) & ~(size_t)255;
        return p;
    };
    int*            bcnt  = (int*)           alloc((size_t)NBUCK * NXCD * 4);
    unsigned int*   arena = (unsigned int*)  alloc((size_t)NBUCK * BSLOTS * 4);
    unsigned short* off16 = (unsigned short*)alloc((size_t)NBUCK * OSTRIDE * 2);
    float*          xA    = (float*)         alloc((size_t)NN * 64 * 4);
    float*          xB    = (float*)         alloc((size_t)NN * 64 * 4);
    unsigned short* xbf   = (unsigned short*)alloc((size_t)NN * 64 * 2);    // bf16 mirror
    unsigned short* Kbuf  = (unsigned short*)alloc((size_t)NN * 256 * 2);   // bf16
    float*          psum  = (float*)         alloc((size_t)NG * 64 * 4);
    int*            pcnt  = (int*)           alloc((size_t)NG * 4);

    hipMemsetAsync(bcnt, 0, (size_t)NBUCK * NXCD * 4, stream);
    hipMemsetAsync(psum, 0, (size_t)NG * 64 * 4, stream);
    hipMemsetAsync(pcnt, 0, (size_t)NG * 4, stream);

    // node features (f32 + bf16 mirror)
    k_embed<<<NN * 64 / 256, 256, 0, stream>>>(x_idx, semb, cemb, lin0w, lin0b, xA, xbf);

    // bucket build (XCD-private) + per-bucket counting sort (once, reused by both layers)
    k_bucket<<<NE / 256, 256, 0, stream>>>(ei, et, bcnt, arena);
    k_sortbucket<<<NBUCK, 256, 0, stream>>>(bcnt, arena, off16);

    // layer 1
    k_agg<<<NN / 4, 256, 0, stream>>>(xbf, arena, off16, Kbuf);
    k_transform<<<(NN / 16 + 7) / 8, 512, 0, stream>>>(Kbuf, r1wrel, r1wroot, r1b, xB, xbf);
    // layer 2
    k_agg<<<NN / 4, 256, 0, stream>>>(xbf, arena, off16, Kbuf);
    k_transform<<<(NN / 16 + 7) / 8, 512, 0, stream>>>(Kbuf, r2wrel, r2wroot, r2b, xA,
                                                       (unsigned short*)nullptr);

    // pool + classify
    {
        int nwaves = (NN + POOL_CHUNK - 1) / POOL_CHUNK;        // 3125
        int nblk = (nwaves * 64 + 255) / 256;                   // 782
        k_pool<<<nblk, 256, 0, stream>>>(xA, batch, psum, pcnt);
    }
    k_cls<<<(NG * 10 + 255) / 256, 256, 0, stream>>>(psum, pcnt, clsw, clsb, out);
}

// Round 15
// 337.757 us; speedup vs baseline: 2.1774x; 1.0414x over previous
//
#include <hip/hip_runtime.h>

#define NN 100000        // nodes
#define NE 1600000       // edges
#define NRL 3            // relations
#define NG 1024          // graphs
#define NBUCK 782        // ceil(NN/128) buckets of 128 nodes
#define NXCD 8
#define PSTRIDE 384      // slots per (bucket, xcd): mean 256, sigma 16 -> +8 sigma
#define BSLOTS (NXCD * PSTRIDE)   // 3072 slots per bucket
#define NKEY 384         // 128 nodes * 3 rel
#define OSTRIDE 392      // u16 offsets per bucket (384 starts + total, padded)

typedef __attribute__((ext_vector_type(8))) short bf16x8;
typedef __attribute__((ext_vector_type(4))) float f32x4;

__device__ __forceinline__ int xcd_id() {
    unsigned int x;
    asm volatile("s_getreg_b32 %0, hwreg(HW_REG_XCC_ID)" : "=s"(x));
    return (int)(x & 7);
}

// f32 -> bf16 with round-to-nearest-even
__device__ __forceinline__ unsigned short f2bf(float f) {
    unsigned u = __float_as_uint(f);
    unsigned r = (u + 0x7fffu + ((u >> 16) & 1u)) >> 16;
    return (unsigned short)r;
}

// ---------------- embed + lin0 + relu (writes f32 x and bf16 mirror) ----------------
__global__ void k_embed(const int* __restrict__ x_idx,
                        const float* __restrict__ semb, const float* __restrict__ cemb,
                        const float* __restrict__ w, const float* __restrict__ b,
                        float* __restrict__ xout, unsigned short* __restrict__ xbf) {
    __shared__ float s_w[16 * 64];
    __shared__ float s_se[64], s_ce[64], s_b[64];
    int t = threadIdx.x;
    for (int i = t; i < 16 * 64; i += 256) s_w[i] = w[i];
    if (t < 64) { s_se[t] = semb[t]; s_ce[t] = cemb[t]; s_b[t] = b[t]; }
    __syncthreads();
    int gid = blockIdx.x * 256 + t;           // grid exactly NN*64/256
    int v = gid >> 6, h = gid & 63;
    int si = x_idx[2 * v], ci = x_idx[2 * v + 1];
    float acc = s_b[h];
#pragma unroll
    for (int d = 0; d < 8; ++d) acc += s_se[si * 8 + d] * s_w[d * 64 + h];
#pragma unroll
    for (int d = 0; d < 8; ++d) acc += s_ce[ci * 8 + d] * s_w[(8 + d) * 64 + h];
    float r = fmaxf(acc, 0.f);
    xout[gid] = r;
    xbf[gid] = f2bf(r);
}

// ---------------- bucket build: XCD-private append, NT streaming reads ----------------
// rec = src (17b) | rel<<17 (2b) | (dst&127)<<19 (7b)
__global__ void k_bucket(const int* __restrict__ ei, const int* __restrict__ et,
                         int* __restrict__ bcnt, unsigned int* __restrict__ arena) {
    int e = blockIdx.x * 256 + threadIdx.x;
    if (e >= NE) return;
    int p = xcd_id();                          // wave-uniform physical XCD
    int src = __builtin_nontemporal_load(ei + e);         // evict-first: don't flush
    int dst = __builtin_nontemporal_load(ei + NE + e);    // the arena write-set out
    int rel = __builtin_nontemporal_load(et + e);         // of L2
    int b = dst >> 7;
    unsigned int rec = (unsigned int)src | ((unsigned int)rel << 17) |
                       ((unsigned int)(dst & 127) << 19);
    int cell = b * NXCD + p;
    int pos = atomicAdd(&bcnt[cell], 1);
    if (pos < PSTRIDE) arena[(size_t)cell * PSTRIDE + pos] = rec;
}

// ---------------- per-bucket LDS counting sort: 8 partitions -> sorted src + offsets ----------------
// key = dstlo*3 + rel (384 keys). Packed sorted writeback at bucket base (stride BSLOTS).
__global__ __launch_bounds__(256) void k_sortbucket(
        const int* __restrict__ bcnt, unsigned int* __restrict__ arena,
        unsigned short* __restrict__ off16) {
    __shared__ unsigned int s_rec[BSLOTS];
    __shared__ unsigned int s_srt[BSLOTS];
    __shared__ int s_hist[NKEY + 1], s_start[NKEY + 1], s_pos[NKEY];
    int t = threadIdx.x;
    int b = blockIdx.x;

    for (int i = t; i < NKEY + 1; i += 256) s_hist[i] = 0;
    __syncthreads();

    int tot = 0;
#pragma unroll
    for (int p = 0; p < NXCD; ++p) {
        int c = bcnt[b * NXCD + p]; if (c > PSTRIDE) c = PSTRIDE;
        const unsigned int* src = arena + ((size_t)(b * NXCD + p)) * PSTRIDE;
        for (int i = t; i < c; i += 256) {
            unsigned int r = __builtin_nontemporal_load(src + i);
            s_rec[tot + i] = r;
            int key = ((r >> 19) & 127) * 3 + ((r >> 17) & 3);
            atomicAdd(&s_hist[key], 1);
        }
        tot += c;
    }
    __syncthreads();
    if (t == 0) {
        int run = 0;
#pragma unroll 8
        for (int k = 0; k < NKEY; ++k) { s_start[k] = run; run += s_hist[k]; }
        s_start[NKEY] = run;                 // == tot
    }
    __syncthreads();
    for (int i = t; i < NKEY; i += 256) s_pos[i] = s_start[i];
    __syncthreads();
    for (int i = t; i < tot; i += 256) {
        unsigned int r = s_rec[i];
        int key = ((r >> 19) & 127) * 3 + ((r >> 17) & 3);
        int p = atomicAdd(&s_pos[key], 1);
        s_srt[p] = r & 0x1FFFF;            // keep src only
    }
    __syncthreads();
    for (int i = t; i < tot; i += 256)      // coalesced packed writeback at bucket base
        arena[(size_t)b * BSLOTS + i] = s_srt[i];
    for (int i = t; i < NKEY + 1; i += 256)
        off16[(size_t)b * OSTRIDE + i] = (unsigned short)s_start[i];
}

// ---------------- per-(r,dst) mean aggregation: wave per node, 2 edges per load ----------------
// Lanes 0-31 process even-slot edge, lanes 32-63 odd-slot edge; each lane holds dims
// (2sl, 2sl+1) as one uint (2 bf16) -> 256B moved per gather instruction. Cross-half
// combine via __shfl_xor(32). K rows written as packed uints by lanes 0-31.
__global__ void k_agg(const unsigned short* __restrict__ xbf,
                      const unsigned int* __restrict__ arena,
                      const unsigned short* __restrict__ off16,
                      unsigned short* __restrict__ K) {
    int wid = (blockIdx.x * 256 + threadIdx.x) >> 6;
    int lane = threadIdx.x & 63;
    if (wid >= NN) return;
    int v = wid;
    int b = v >> 7, dlo = v & 127;
    const unsigned short* ofs = off16 + (size_t)b * OSTRIDE + dlo * 3;
    int s0 = __builtin_amdgcn_readfirstlane((int)ofs[0]);
    int s1 = __builtin_amdgcn_readfirstlane((int)ofs[1]);
    int s2 = __builtin_amdgcn_readfirstlane((int)ofs[2]);
    int s3 = __builtin_amdgcn_readfirstlane((int)ofs[3]);
    const unsigned int* base = arena + (size_t)b * BSLOTS;

    int half = lane >> 5, sl = lane & 31;
    float2 a0 = {0.f, 0.f}, a1 = {0.f, 0.f}, a2 = {0.f, 0.f};

    int e = s0;
    for (; e + 8 <= s3; e += 8) {
#pragma unroll
        for (int k = 0; k < 4; ++k) {
            int ee = e + 2 * k + half;
            int idx = (int)base[ee];
            unsigned u = *reinterpret_cast<const unsigned*>(
                             xbf + (size_t)idx * 64 + 2 * sl);
            float f0 = __uint_as_float(u << 16);          // dim 2sl
            float f1 = __uint_as_float(u & 0xFFFF0000u);  // dim 2sl+1
            bool c0 = ee < s1;
            bool c2 = ee >= s2;
            bool c1 = !c0 && !c2;
            a0.x += c0 ? f0 : 0.f;  a0.y += c0 ? f1 : 0.f;
            a1.x += c1 ? f0 : 0.f;  a1.y += c1 ? f1 : 0.f;
            a2.x += c2 ? f0 : 0.f;  a2.y += c2 ? f1 : 0.f;
        }
    }
    for (; e < s3; e += 2) {
        int ee = e + half;
        bool ok = ee < s3;
        int idx = (int)base[ok ? ee : e];
        unsigned u = *reinterpret_cast<const unsigned*>(
                         xbf + (size_t)idx * 64 + 2 * sl);
        float f0 = __uint_as_float(u << 16);
        float f1 = __uint_as_float(u & 0xFFFF0000u);
        bool c0 = ok && (ee < s1);
        bool c2 = ok && (ee >= s2);
        bool c1 = ok && !(ee < s1) && (ee < s2);
        a0.x += c0 ? f0 : 0.f;  a0.y += c0 ? f1 : 0.f;
        a1.x += c1 ? f0 : 0.f;  a1.y += c1 ? f1 : 0.f;
        a2.x += c2 ? f0 : 0.f;  a2.y += c2 ? f1 : 0.f;
    }

    a0.x += __shfl_xor(a0.x, 32);  a0.y += __shfl_xor(a0.y, 32);
    a1.x += __shfl_xor(a1.x, 32);  a1.y += __shfl_xor(a1.y, 32);
    a2.x += __shfl_xor(a2.x, 32);  a2.y += __shfl_xor(a2.y, 32);

    unsigned short* Kv = K + (size_t)v * 256;
    if (lane < 32) {
        float d0 = fmaxf((float)(s1 - s0), 1.f);
        float d1 = fmaxf((float)(s2 - s1), 1.f);
        float d2 = fmaxf((float)(s3 - s2), 1.f);
        unsigned p0 = (unsigned)f2bf(a0.x / d0) | ((unsigned)f2bf(a0.y / d0) << 16);
        unsigned p1 = (unsigned)f2bf(a1.x / d1) | ((unsigned)f2bf(a1.y / d1) << 16);
        unsigned p2 = (unsigned)f2bf(a2.x / d2) | ((unsigned)f2bf(a2.y / d2) << 16);
        unsigned* Kw = reinterpret_cast<unsigned*>(Kv);
        Kw[sl]      = p0;          // dims 2sl,2sl+1 of mean_r0
        Kw[32 + sl] = p1;
        Kw[64 + sl] = p2;
    }
    Kv[192 + lane] = xbf[(size_t)v * 64 + lane];    // exact self copy
}

// ---------------- dense transform via MFMA: xout = relu(K @ [Wr;Wroot] + b) ----------------
// v_mfma_f32_16x16x32_bf16. Wave = 16-node strip x 64 h (4 C-tiles). 8 K-iters of 32.
// A frag from global bf16 K (16B vector load); B frag (bf16 W) staged in LDS in frag
// order with the SAME k-map as A. C/D layout (m89): col=lane&15, row=(lane>>4)*4+reg.
// Optionally writes the bf16 mirror for the next layer's agg.
__global__ __launch_bounds__(512, 4) void k_transform(
        const unsigned short* __restrict__ K, const float* __restrict__ wrel,
        const float* __restrict__ wroot, const float* __restrict__ b,
        float* __restrict__ xout, unsigned short* __restrict__ xbf) {
    __shared__ __align__(16) unsigned short s_bf[4][8][64][8];  // [ntile][kiter][lane][j]
    __shared__ float s_b[64];
    int t = threadIdx.x;
    for (int i = t; i < 4 * 8 * 64 * 8; i += 512) {
        int j  = i & 7;
        int l  = (i >> 3) & 63;
        int c  = (i >> 9) & 7;
        int nt = (i >> 12) & 3;
        int k  = c * 32 + (l >> 4) * 8 + j;     // same k-map as the A load below
        int n  = nt * 16 + (l & 15);
        const float* src = (k < 192) ? (wrel + k * 64 + n) : (wroot + (k - 192) * 64 + n);
        s_bf[nt][c][l][j] = f2bf(*src);
    }
    if (t < 64) s_b[t] = b[t];
    __syncthreads();

    int wave = t >> 6, lane = t & 63;
    int strip = blockIdx.x * 8 + wave;
    if (strip > NN / 16 - 1) strip = NN / 16 - 1;   // dup strips write identical data
    int v0 = strip * 16;

    const unsigned short* Ka = K + (size_t)(v0 + (lane & 15)) * 256 + (lane >> 4) * 8;

    f32x4 acc0 = {0.f, 0.f, 0.f, 0.f};
    f32x4 acc1 = {0.f, 0.f, 0.f, 0.f};
    f32x4 acc2 = {0.f, 0.f, 0.f, 0.f};
    f32x4 acc3 = {0.f, 0.f, 0.f, 0.f};

#pragma unroll
    for (int c = 0; c < 8; ++c) {
        bf16x8 a = *reinterpret_cast<const bf16x8*>(Ka + c * 32);
        bf16x8 b0 = *reinterpret_cast<const bf16x8*>(&s_bf[0][c][lane][0]);
        bf16x8 b1 = *reinterpret_cast<const bf16x8*>(&s_bf[1][c][lane][0]);
        bf16x8 b2 = *reinterpret_cast<const bf16x8*>(&s_bf[2][c][lane][0]);
        bf16x8 b3 = *reinterpret_cast<const bf16x8*>(&s_bf[3][c][lane][0]);
        acc0 = __builtin_amdgcn_mfma_f32_16x16x32_bf16(a, b0, acc0, 0, 0, 0);
        acc1 = __builtin_amdgcn_mfma_f32_16x16x32_bf16(a, b1, acc1, 0, 0, 0);
        acc2 = __builtin_amdgcn_mfma_f32_16x16x32_bf16(a, b2, acc2, 0, 0, 0);
        acc3 = __builtin_amdgcn_mfma_f32_16x16x32_bf16(a, b3, acc3, 0, 0, 0);
    }

    int col = lane & 15, rg = (lane >> 4) * 4;
#pragma unroll
    for (int r = 0; r < 4; ++r) {
        float o0 = fmaxf(acc0[r] + s_b[0  + col], 0.f);
        float o1 = fmaxf(acc1[r] + s_b[16 + col], 0.f);
        float o2 = fmaxf(acc2[r] + s_b[32 + col], 0.f);
        float o3 = fmaxf(acc3[r] + s_b[48 + col], 0.f);
        float* op = xout + (size_t)(v0 + rg + r) * 64;
        op[0  + col] = o0;
        op[16 + col] = o1;
        op[32 + col] = o2;
        op[48 + col] = o3;
        if (xbf) {
            unsigned short* ob = xbf + (size_t)(v0 + rg + r) * 64;
            ob[0  + col] = f2bf(o0);
            ob[16 + col] = f2bf(o1);
            ob[32 + col] = f2bf(o2);
            ob[48 + col] = f2bf(o3);
        }
    }
}

// ---------------- global mean pool: wave-segmented over sorted batch ----------------
#define POOL_CHUNK 32
__global__ void k_pool(const float* __restrict__ x, const int* __restrict__ batch,
                       float* __restrict__ psum, int* __restrict__ pcnt) {
    int gwid = (blockIdx.x * 256 + threadIdx.x) >> 6;
    int lane = threadIdx.x & 63;
    int v0 = gwid * POOL_CHUNK;
    if (v0 >= NN) return;
    int v1 = v0 + POOL_CHUNK; if (v1 > NN) v1 = NN;
    float acc = 0.f;
    int cnt = 0;
    int gcur = batch[v0];
    for (int v = v0; v < v1; ++v) {
        int g = batch[v];
        if (g != gcur) {
            atomicAdd(&psum[gcur * 64 + lane], acc);
            if (lane == 0) atomicAdd(&pcnt[gcur], cnt);
            acc = 0.f; cnt = 0; gcur = g;
        }
        acc += x[(size_t)v * 64 + lane];
        ++cnt;
    }
    atomicAdd(&psum[gcur * 64 + lane], acc);
    if (lane == 0) atomicAdd(&pcnt[gcur], cnt);
}

__global__ void k_cls(const float* __restrict__ psum, const int* __restrict__ pcnt,
                      const float* __restrict__ w, const float* __restrict__ b,
                      float* __restrict__ out) {
    int gid = blockIdx.x * 256 + threadIdx.x;
    if (gid >= NG * 10) return;
    int g = gid / 10, c = gid % 10;
    float inv = 1.f / fmaxf((float)pcnt[g], 1.f);
    float acc = 0.f;
#pragma unroll
    for (int d = 0; d < 64; ++d) acc += psum[g * 64 + d] * w[d * 10 + c];
    out[gid] = acc * inv + b[c];
}

extern "C" void kernel_launch(void* const* d_in, const int* in_sizes, int n_in,
                              void* d_out, int out_size, void* d_ws, size_t ws_size,
                              hipStream_t stream) {
    const int*   x_idx  = (const int*)d_in[0];
    const int*   ei     = (const int*)d_in[1];
    const int*   et     = (const int*)d_in[2];
    const int*   batch  = (const int*)d_in[3];
    const float* semb   = (const float*)d_in[4];
    const float* cemb   = (const float*)d_in[5];
    const float* lin0w  = (const float*)d_in[6];
    const float* lin0b  = (const float*)d_in[7];
    const float* r1wrel = (const float*)d_in[8];
    const float* r1wroot= (const float*)d_in[9];
    const float* r1b    = (const float*)d_in[10];
    const float* r2wrel = (const float*)d_in[11];
    const float* r2wroot= (const float*)d_in[12];
    const float* r2b    = (const float*)d_in[13];
    const float* clsw   = (const float*)d_in[14];
    const float* clsb   = (const float*)d_in[15];
    float* out = (float*)d_out;

    char* ws = (char*)d_ws;
    size_t o = 0;
    auto alloc = [&](size_t bytes) -> void* {
        void* p = ws + o;
        o += (bytes + 255) & ~(size_t)255;
        return p;
    };
    int*            bcnt  = (int*)           alloc((size_t)NBUCK * NXCD * 4);
    unsigned int*   arena = (unsigned int*)  alloc((size_t)NBUCK * BSLOTS * 4);
    unsigned short* off16 = (unsigned short*)alloc((size_t)NBUCK * OSTRIDE * 2);
    float*          xA    = (float*)         alloc((size_t)NN * 64 * 4);
    float*          xB    = (float*)         alloc((size_t)NN * 64 * 4);
    unsigned short* xbf   = (unsigned short*)alloc((size_t)NN * 64 * 2);    // bf16 mirror
    unsigned short* Kbuf  = (unsigned short*)alloc((size_t)NN * 256 * 2);   // bf16
    float*          psum  = (float*)         alloc((size_t)NG * 64 * 4);
    int*            pcnt  = (int*)           alloc((size_t)NG * 4);

    hipMemsetAsync(bcnt, 0, (size_t)NBUCK * NXCD * 4, stream);
    hipMemsetAsync(psum, 0, (size_t)NG * 64 * 4, stream);
    hipMemsetAsync(pcnt, 0, (size_t)NG * 4, stream);

    // node features (f32 + bf16 mirror)
    k_embed<<<NN * 64 / 256, 256, 0, stream>>>(x_idx, semb, cemb, lin0w, lin0b, xA, xbf);

    // bucket build (XCD-private) + per-bucket counting sort (once, reused by both layers)
    k_bucket<<<NE / 256, 256, 0, stream>>>(ei, et, bcnt, arena);
    k_sortbucket<<<NBUCK, 256, 0, stream>>>(bcnt, arena, off16);

    // layer 1
    k_agg<<<NN / 4, 256, 0, stream>>>(xbf, arena, off16, Kbuf);
    k_transform<<<(NN / 16 + 7) / 8, 512, 0, stream>>>(Kbuf, r1wrel, r1wroot, r1b, xB, xbf);
    // layer 2
    k_agg<<<NN / 4, 256, 0, stream>>>(xbf, arena, off16, Kbuf);
    k_transform<<<(NN / 16 + 7) / 8, 512, 0, stream>>>(Kbuf, r2wrel, r2wroot, r2b, xA,
                                                       (unsigned short*)nullptr);

    // pool + classify
    {
        int nwaves = (NN + POOL_CHUNK - 1) / POOL_CHUNK;        // 3125
        int nblk = (nwaves * 64 + 255) / 256;                   // 782
        k_pool<<<nblk, 256, 0, stream>>>(xA, batch, psum, pcnt);
    }
    k_cls<<<(NG * 10 + 255) / 256, 256, 0, stream>>>(psum, pcnt, clsw, clsb, out);
}

// Round 16
// 298.819 us; speedup vs baseline: 2.4612x; 1.1303x over previous
//
#include <hip/hip_runtime.h>

#define NN 100000        // nodes
#define NE 1600000       // edges
#define NRL 3            // relations
#define NG 1024          // graphs
#define NBUCK 782        // ceil(NN/128) buckets of 128 nodes
#define NXCD 8
#define PSTRIDE 384      // slots per (bucket, xcd): mean 256, sigma 16 -> +8 sigma
#define BSLOTS (NXCD * PSTRIDE)   // 3072 slots per bucket
#define NKEY 384         // 128 nodes * 3 rel
#define OSTRIDE 392      // u16 offsets per bucket (384 starts + total, padded)
#define EB 4096          // edges per k_bucket block

typedef __attribute__((ext_vector_type(8))) short bf16x8;
typedef __attribute__((ext_vector_type(4))) float f32x4;

__device__ __forceinline__ int xcd_id() {
    unsigned int x;
    asm volatile("s_getreg_b32 %0, hwreg(HW_REG_XCC_ID)" : "=s"(x));
    return (int)(x & 7);
}

// f32 -> bf16 with round-to-nearest-even
__device__ __forceinline__ unsigned short f2bf(float f) {
    unsigned u = __float_as_uint(f);
    unsigned r = (u + 0x7fffu + ((u >> 16) & 1u)) >> 16;
    return (unsigned short)r;
}

// ---------------- embed + lin0 + relu (writes f32 x and bf16 mirror) ----------------
__global__ void k_embed(const int* __restrict__ x_idx,
                        const float* __restrict__ semb, const float* __restrict__ cemb,
                        const float* __restrict__ w, const float* __restrict__ b,
                        float* __restrict__ xout, unsigned short* __restrict__ xbf) {
    __shared__ float s_w[16 * 64];
    __shared__ float s_se[64], s_ce[64], s_b[64];
    int t = threadIdx.x;
    for (int i = t; i < 16 * 64; i += 256) s_w[i] = w[i];
    if (t < 64) { s_se[t] = semb[t]; s_ce[t] = cemb[t]; s_b[t] = b[t]; }
    __syncthreads();
    int gid = blockIdx.x * 256 + t;           // grid exactly NN*64/256
    int v = gid >> 6, h = gid & 63;
    int si = x_idx[2 * v], ci = x_idx[2 * v + 1];
    float acc = s_b[h];
#pragma unroll
    for (int d = 0; d < 8; ++d) acc += s_se[si * 8 + d] * s_w[d * 64 + h];
#pragma unroll
    for (int d = 0; d < 8; ++d) acc += s_ce[ci * 8 + d] * s_w[(8 + d) * 64 + h];
    float r = fmaxf(acc, 0.f);
    xout[gid] = r;
    xbf[gid] = f2bf(r);
}

// ---------------- bucket build: LDS-binned, run-coalesced writeback ----------------
// Block bins EB edges by bucket in LDS, reserves one contiguous run per (bucket,xcd)
// via a single atomic, then writes records in sorted order: consecutive threads in
// the same bucket run hit adjacent addresses -> coalesced run transactions.
// rec = src (17b) | rel<<17 (2b) | (dst&127)<<19 (7b)
__global__ __launch_bounds__(256) void k_bucket(
        const int* __restrict__ ei, const int* __restrict__ et,
        int* __restrict__ bcnt, unsigned int* __restrict__ arena) {
    __shared__ unsigned int   s_srt[EB];
    __shared__ unsigned short s_skey[EB];
    __shared__ int s_hist[NBUCK], s_start[NBUCK + 1], s_base[NBUCK], s_pos[NBUCK];
    int t = threadIdx.x;
    int e0 = blockIdx.x * EB;
    int n = NE - e0; if (n > EB) n = EB;
    int p = xcd_id();                              // block-uniform (block lives on 1 CU)

    for (int i = t; i < NBUCK; i += 256) s_hist[i] = 0;
    __syncthreads();

    // pass 1: histogram buckets
    for (int i = t; i < n; i += 256) {
        int dst = __builtin_nontemporal_load(ei + NE + e0 + i);
        atomicAdd(&s_hist[dst >> 7], 1);
    }
    __syncthreads();
    if (t == 0) {
        int run = 0;
#pragma unroll 8
        for (int k = 0; k < NBUCK; ++k) { s_start[k] = run; run += s_hist[k]; }
        s_start[NBUCK] = run;
    }
    __syncthreads();
    // reserve global runs (one atomic per non-empty bucket)
    for (int k = t; k < NBUCK; k += 256) {
        s_pos[k] = s_start[k];
        s_base[k] = (s_hist[k] > 0) ? atomicAdd(&bcnt[k * NXCD + p], s_hist[k]) : 0;
    }
    __syncthreads();

    // pass 2: scatter records into LDS in bucket-sorted order
    for (int i = t; i < n; i += 256) {
        int e = e0 + i;
        int src = __builtin_nontemporal_load(ei + e);
        int dst = __builtin_nontemporal_load(ei + NE + e);
        int rel = __builtin_nontemporal_load(et + e);
        int key = dst >> 7;
        unsigned int rec = (unsigned int)src | ((unsigned int)rel << 17) |
                           ((unsigned int)(dst & 127) << 19);
        int q = atomicAdd(&s_pos[key], 1);
        s_srt[q] = rec;
        s_skey[q] = (unsigned short)key;
    }
    __syncthreads();

    // coalesced writeback: sorted index i -> arena[(key,xcd) partition, base + rank]
    for (int i = t; i < n; i += 256) {
        int key = (int)s_skey[i];
        int off = s_base[key] + (i - s_start[key]);
        if (off < PSTRIDE)
            arena[((size_t)key * NXCD + p) * PSTRIDE + off] = s_srt[i];
    }
}

// ---------------- per-bucket LDS counting sort: 8 partitions -> sorted src + offsets ----------------
// key = dstlo*3 + rel (384 keys). Packed sorted writeback at bucket base (stride BSLOTS).
__global__ __launch_bounds__(256) void k_sortbucket(
        const int* __restrict__ bcnt, unsigned int* __restrict__ arena,
        unsigned short* __restrict__ off16) {
    __shared__ unsigned int s_rec[BSLOTS];
    __shared__ unsigned int s_srt[BSLOTS];
    __shared__ int s_hist[NKEY + 1], s_start[NKEY + 1], s_pos[NKEY];
    int t = threadIdx.x;
    int b = blockIdx.x;

    for (int i = t; i < NKEY + 1; i += 256) s_hist[i] = 0;
    __syncthreads();

    int tot = 0;
#pragma unroll
    for (int p = 0; p < NXCD; ++p) {
        int c = bcnt[b * NXCD + p]; if (c > PSTRIDE) c = PSTRIDE;
        const unsigned int* src = arena + ((size_t)(b * NXCD + p)) * PSTRIDE;
        for (int i = t; i < c; i += 256) {
            unsigned int r = __builtin_nontemporal_load(src + i);
            s_rec[tot + i] = r;
            int key = ((r >> 19) & 127) * 3 + ((r >> 17) & 3);
            atomicAdd(&s_hist[key], 1);
        }
        tot += c;
    }
    __syncthreads();
    if (t == 0) {
        int run = 0;
#pragma unroll 8
        for (int k = 0; k < NKEY; ++k) { s_start[k] = run; run += s_hist[k]; }
        s_start[NKEY] = run;                 // == tot
    }
    __syncthreads();
    for (int i = t; i < NKEY; i += 256) s_pos[i] = s_start[i];
    __syncthreads();
    for (int i = t; i < tot; i += 256) {
        unsigned int r = s_rec[i];
        int key = ((r >> 19) & 127) * 3 + ((r >> 17) & 3);
        int p = atomicAdd(&s_pos[key], 1);
        s_srt[p] = r & 0x1FFFF;            // keep src only
    }
    __syncthreads();
    for (int i = t; i < tot; i += 256)      // coalesced packed writeback at bucket base
        arena[(size_t)b * BSLOTS + i] = s_srt[i];
    for (int i = t; i < NKEY + 1; i += 256)
        off16[(size_t)b * OSTRIDE + i] = (unsigned short)s_start[i];
}

// ---------------- per-(r,dst) mean aggregation: wave per node, 2 edges per load ----------------
// Lanes 0-31 process even-slot edge, lanes 32-63 odd-slot edge; each lane holds dims
// (2sl, 2sl+1) as one uint (2 bf16) -> 256B moved per gather instruction. Cross-half
// combine via __shfl_xor(32). K rows written as packed uints by lanes 0-31.
__global__ void k_agg(const unsigned short* __restrict__ xbf,
                      const unsigned int* __restrict__ arena,
                      const unsigned short* __restrict__ off16,
                      unsigned short* __restrict__ K) {
    int wid = (blockIdx.x * 256 + threadIdx.x) >> 6;
    int lane = threadIdx.x & 63;
    if (wid >= NN) return;
    int v = wid;
    int b = v >> 7, dlo = v & 127;
    const unsigned short* ofs = off16 + (size_t)b * OSTRIDE + dlo * 3;
    int s0 = __builtin_amdgcn_readfirstlane((int)ofs[0]);
    int s1 = __builtin_amdgcn_readfirstlane((int)ofs[1]);
    int s2 = __builtin_amdgcn_readfirstlane((int)ofs[2]);
    int s3 = __builtin_amdgcn_readfirstlane((int)ofs[3]);
    const unsigned int* base = arena + (size_t)b * BSLOTS;

    int half = lane >> 5, sl = lane & 31;
    float2 a0 = {0.f, 0.f}, a1 = {0.f, 0.f}, a2 = {0.f, 0.f};

    int e = s0;
    for (; e + 8 <= s3; e += 8) {
#pragma unroll
        for (int k = 0; k < 4; ++k) {
            int ee = e + 2 * k + half;
            int idx = (int)base[ee];
            unsigned u = *reinterpret_cast<const unsigned*>(
                             xbf + (size_t)idx * 64 + 2 * sl);
            float f0 = __uint_as_float(u << 16);          // dim 2sl
            float f1 = __uint_as_float(u & 0xFFFF0000u);  // dim 2sl+1
            bool c0 = ee < s1;
            bool c2 = ee >= s2;
            bool c1 = !c0 && !c2;
            a0.x += c0 ? f0 : 0.f;  a0.y += c0 ? f1 : 0.f;
            a1.x += c1 ? f0 : 0.f;  a1.y += c1 ? f1 : 0.f;
            a2.x += c2 ? f0 : 0.f;  a2.y += c2 ? f1 : 0.f;
        }
    }
    for (; e < s3; e += 2) {
        int ee = e + half;
        bool ok = ee < s3;
        int idx = (int)base[ok ? ee : e];
        unsigned u = *reinterpret_cast<const unsigned*>(
                         xbf + (size_t)idx * 64 + 2 * sl);
        float f0 = __uint_as_float(u << 16);
        float f1 = __uint_as_float(u & 0xFFFF0000u);
        bool c0 = ok && (ee < s1);
        bool c2 = ok && (ee >= s2);
        bool c1 = ok && !(ee < s1) && (ee < s2);
        a0.x += c0 ? f0 : 0.f;  a0.y += c0 ? f1 : 0.f;
        a1.x += c1 ? f0 : 0.f;  a1.y += c1 ? f1 : 0.f;
        a2.x += c2 ? f0 : 0.f;  a2.y += c2 ? f1 : 0.f;
    }

    a0.x += __shfl_xor(a0.x, 32);  a0.y += __shfl_xor(a0.y, 32);
    a1.x += __shfl_xor(a1.x, 32);  a1.y += __shfl_xor(a1.y, 32);
    a2.x += __shfl_xor(a2.x, 32);  a2.y += __shfl_xor(a2.y, 32);

    unsigned short* Kv = K + (size_t)v * 256;
    if (lane < 32) {
        float d0 = fmaxf((float)(s1 - s0), 1.f);
        float d1 = fmaxf((float)(s2 - s1), 1.f);
        float d2 = fmaxf((float)(s3 - s2), 1.f);
        unsigned p0 = (unsigned)f2bf(a0.x / d0) | ((unsigned)f2bf(a0.y / d0) << 16);
        unsigned p1 = (unsigned)f2bf(a1.x / d1) | ((unsigned)f2bf(a1.y / d1) << 16);
        unsigned p2 = (unsigned)f2bf(a2.x / d2) | ((unsigned)f2bf(a2.y / d2) << 16);
        unsigned* Kw = reinterpret_cast<unsigned*>(Kv);
        Kw[sl]      = p0;          // dims 2sl,2sl+1 of mean_r0
        Kw[32 + sl] = p1;
        Kw[64 + sl] = p2;
    }
    Kv[192 + lane] = xbf[(size_t)v * 64 + lane];    // exact self copy
}

// ---------------- dense transform via MFMA: xout = relu(K @ [Wr;Wroot] + b) ----------------
// v_mfma_f32_16x16x32_bf16. Wave = 16-node strip x 64 h (4 C-tiles). 8 K-iters of 32.
// A frag from global bf16 K (16B vector load); B frag (bf16 W) staged in LDS in frag
// order with the SAME k-map as A. C/D layout (m89): col=lane&15, row=(lane>>4)*4+reg.
// Optionally writes the bf16 mirror for the next layer's agg.
__global__ __launch_bounds__(512, 4) void k_transform(
        const unsigned short* __restrict__ K, const float* __restrict__ wrel,
        const float* __restrict__ wroot, const float* __restrict__ b,
        float* __restrict__ xout, unsigned short* __restrict__ xbf) {
    __shared__ __align__(16) unsigned short s_bf[4][8][64][8];  // [ntile][kiter][lane][j]
    __shared__ float s_b[64];
    int t = threadIdx.x;
    for (int i = t; i < 4 * 8 * 64 * 8; i += 512) {
        int j  = i & 7;
        int l  = (i >> 3) & 63;
        int c  = (i >> 9) & 7;
        int nt = (i >> 12) & 3;
        int k  = c * 32 + (l >> 4) * 8 + j;     // same k-map as the A load below
        int n  = nt * 16 + (l & 15);
        const float* src = (k < 192) ? (wrel + k * 64 + n) : (wroot + (k - 192) * 64 + n);
        s_bf[nt][c][l][j] = f2bf(*src);
    }
    if (t < 64) s_b[t] = b[t];
    __syncthreads();

    int wave = t >> 6, lane = t & 63;
    int strip = blockIdx.x * 8 + wave;
    if (strip > NN / 16 - 1) strip = NN / 16 - 1;   // dup strips write identical data
    int v0 = strip * 16;

    const unsigned short* Ka = K + (size_t)(v0 + (lane & 15)) * 256 + (lane >> 4) * 8;

    f32x4 acc0 = {0.f, 0.f, 0.f, 0.f};
    f32x4 acc1 = {0.f, 0.f, 0.f, 0.f};
    f32x4 acc2 = {0.f, 0.f, 0.f, 0.f};
    f32x4 acc3 = {0.f, 0.f, 0.f, 0.f};

#pragma unroll
    for (int c = 0; c < 8; ++c) {
        bf16x8 a = *reinterpret_cast<const bf16x8*>(Ka + c * 32);
        bf16x8 b0 = *reinterpret_cast<const bf16x8*>(&s_bf[0][c][lane][0]);
        bf16x8 b1 = *reinterpret_cast<const bf16x8*>(&s_bf[1][c][lane][0]);
        bf16x8 b2 = *reinterpret_cast<const bf16x8*>(&s_bf[2][c][lane][0]);
        bf16x8 b3 = *reinterpret_cast<const bf16x8*>(&s_bf[3][c][lane][0]);
        acc0 = __builtin_amdgcn_mfma_f32_16x16x32_bf16(a, b0, acc0, 0, 0, 0);
        acc1 = __builtin_amdgcn_mfma_f32_16x16x32_bf16(a, b1, acc1, 0, 0, 0);
        acc2 = __builtin_amdgcn_mfma_f32_16x16x32_bf16(a, b2, acc2, 0, 0, 0);
        acc3 = __builtin_amdgcn_mfma_f32_16x16x32_bf16(a, b3, acc3, 0, 0, 0);
    }

    int col = lane & 15, rg = (lane >> 4) * 4;
#pragma unroll
    for (int r = 0; r < 4; ++r) {
        float o0 = fmaxf(acc0[r] + s_b[0  + col], 0.f);
        float o1 = fmaxf(acc1[r] + s_b[16 + col], 0.f);
        float o2 = fmaxf(acc2[r] + s_b[32 + col], 0.f);
        float o3 = fmaxf(acc3[r] + s_b[48 + col], 0.f);
        float* op = xout + (size_t)(v0 + rg + r) * 64;
        op[0  + col] = o0;
        op[16 + col] = o1;
        op[32 + col] = o2;
        op[48 + col] = o3;
        if (xbf) {
            unsigned short* ob = xbf + (size_t)(v0 + rg + r) * 64;
            ob[0  + col] = f2bf(o0);
            ob[16 + col] = f2bf(o1);
            ob[32 + col] = f2bf(o2);
            ob[48 + col] = f2bf(o3);
        }
    }
}

// ---------------- global mean pool: wave-segmented over sorted batch ----------------
#define POOL_CHUNK 32
__global__ void k_pool(const float* __restrict__ x, const int* __restrict__ batch,
                       float* __restrict__ psum, int* __restrict__ pcnt) {
    int gwid = (blockIdx.x * 256 + threadIdx.x) >> 6;
    int lane = threadIdx.x & 63;
    int v0 = gwid * POOL_CHUNK;
    if (v0 >= NN) return;
    int v1 = v0 + POOL_CHUNK; if (v1 > NN) v1 = NN;
    float acc = 0.f;
    int cnt = 0;
    int gcur = batch[v0];
    for (int v = v0; v < v1; ++v) {
        int g = batch[v];
        if (g != gcur) {
            atomicAdd(&psum[gcur * 64 + lane], acc);
            if (lane == 0) atomicAdd(&pcnt[gcur], cnt);
            acc = 0.f; cnt = 0; gcur = g;
        }
        acc += x[(size_t)v * 64 + lane];
        ++cnt;
    }
    atomicAdd(&psum[gcur * 64 + lane], acc);
    if (lane == 0) atomicAdd(&pcnt[gcur], cnt);
}

__global__ void k_cls(const float* __restrict__ psum, const int* __restrict__ pcnt,
                      const float* __restrict__ w, const float* __restrict__ b,
                      float* __restrict__ out) {
    int gid = blockIdx.x * 256 + threadIdx.x;
    if (gid >= NG * 10) return;
    int g = gid / 10, c = gid % 10;
    float inv = 1.f / fmaxf((float)pcnt[g], 1.f);
    float acc = 0.f;
#pragma unroll
    for (int d = 0; d < 64; ++d) acc += psum[g * 64 + d] * w[d * 10 + c];
    out[gid] = acc * inv + b[c];
}

extern "C" void kernel_launch(void* const* d_in, const int* in_sizes, int n_in,
                              void* d_out, int out_size, void* d_ws, size_t ws_size,
                              hipStream_t stream) {
    const int*   x_idx  = (const int*)d_in[0];
    const int*   ei     = (const int*)d_in[1];
    const int*   et     = (const int*)d_in[2];
    const int*   batch  = (const int*)d_in[3];
    const float* semb   = (const float*)d_in[4];
    const float* cemb   = (const float*)d_in[5];
    const float* lin0w  = (const float*)d_in[6];
    const float* lin0b  = (const float*)d_in[7];
    const float* r1wrel = (const float*)d_in[8];
    const float* r1wroot= (const float*)d_in[9];
    const float* r1b    = (const float*)d_in[10];
    const float* r2wrel = (const float*)d_in[11];
    const float* r2wroot= (const float*)d_in[12];
    const float* r2b    = (const float*)d_in[13];
    const float* clsw   = (const float*)d_in[14];
    const float* clsb   = (const float*)d_in[15];
    float* out = (float*)d_out;

    char* ws = (char*)d_ws;
    size_t o = 0;
    auto alloc = [&](size_t bytes) -> void* {
        void* p = ws + o;
        o += (bytes + 255) & ~(size_t)255;
        return p;
    };
    int*            bcnt  = (int*)           alloc((size_t)NBUCK * NXCD * 4);
    unsigned int*   arena = (unsigned int*)  alloc((size_t)NBUCK * BSLOTS * 4);
    unsigned short* off16 = (unsigned short*)alloc((size_t)NBUCK * OSTRIDE * 2);
    float*          xA    = (float*)         alloc((size_t)NN * 64 * 4);
    float*          xB    = (float*)         alloc((size_t)NN * 64 * 4);
    unsigned short* xbf   = (unsigned short*)alloc((size_t)NN * 64 * 2);    // bf16 mirror
    unsigned short* Kbuf  = (unsigned short*)alloc((size_t)NN * 256 * 2);   // bf16
    float*          psum  = (float*)         alloc((size_t)NG * 64 * 4);
    int*            pcnt  = (int*)           alloc((size_t)NG * 4);

    hipMemsetAsync(bcnt, 0, (size_t)NBUCK * NXCD * 4, stream);
    hipMemsetAsync(psum, 0, (size_t)NG * 64 * 4, stream);
    hipMemsetAsync(pcnt, 0, (size_t)NG * 4, stream);

    // node features (f32 + bf16 mirror)
    k_embed<<<NN * 64 / 256, 256, 0, stream>>>(x_idx, semb, cemb, lin0w, lin0b, xA, xbf);

    // bucket build (LDS-binned, XCD-private) + per-bucket counting sort (once, both layers)
    k_bucket<<<(NE + EB - 1) / EB, 256, 0, stream>>>(ei, et, bcnt, arena);
    k_sortbucket<<<NBUCK, 256, 0, stream>>>(bcnt, arena, off16);

    // layer 1
    k_agg<<<NN / 4, 256, 0, stream>>>(xbf, arena, off16, Kbuf);
    k_transform<<<(NN / 16 + 7) / 8, 512, 0, stream>>>(Kbuf, r1wrel, r1wroot, r1b, xB, xbf);
    // layer 2
    k_agg<<<NN / 4, 256, 0, stream>>>(xbf, arena, off16, Kbuf);
    k_transform<<<(NN / 16 + 7) / 8, 512, 0, stream>>>(Kbuf, r2wrel, r2wroot, r2b, xA,
                                                       (unsigned short*)nullptr);

    // pool + classify
    {
        int nwaves = (NN + POOL_CHUNK - 1) / POOL_CHUNK;        // 3125
        int nblk = (nwaves * 64 + 255) / 256;                   // 782
        k_pool<<<nblk, 256, 0, stream>>>(xA, batch, psum, pcnt);
    }
    k_cls<<<(NG * 10 + 255) / 256, 256, 0, stream>>>(psum, pcnt, clsw, clsb, out);
}